// Round 5
// baseline (189.914 us; speedup 1.0000x reference)
//
#include <hip/hip_runtime.h>
#include <hip/hip_bf16.h>
#include <math.h>

#define B_ 4
#define N_ 2048
#define D_ 256
#define H_ 8
#define HD_ 32
#define F_ 1024
#define M_ (B_*N_)
#define EPS_ 1e-5f
#define KV_ 128
#define KPAD 136

typedef __attribute__((ext_vector_type(8))) short short8;
typedef __attribute__((ext_vector_type(4))) float f32x4;

// log2(e)/sqrt(32): folded into Q so softmax uses exp2 directly
#define QSC 0.2550565499f

__device__ inline unsigned short f2bf(float f) {
    union { float f; unsigned u; } x; x.f = f;
    unsigned r = x.u + 0x7fff + ((x.u >> 16) & 1);
    return (unsigned short)(r >> 16);
}

__device__ inline unsigned pk_bf16(float a, float b) {
    union { __hip_bfloat162 h; unsigned u; } c;
    c.h = __float22bfloat162_rn(float2{a, b});
    return c.u;
}

__device__ inline void async_copy16(const void* g, void* l) {
    __builtin_amdgcn_global_load_lds(
        (const __attribute__((address_space(1))) void*)g,
        (__attribute__((address_space(3))) void*)l, 16, 0, 0);
}

// ---------------- LayerNorm (one block per row of 256), bf16 out ------------
template<int BF16OUT>
__global__ __launch_bounds__(256) void ln_kernel(const float* __restrict__ x,
        const float* __restrict__ g, const float* __restrict__ be,
        void* __restrict__ out) {
    int row = blockIdx.x;
    int tid = threadIdx.x;
    float v = x[(size_t)row * D_ + tid];
    float s = v, s2 = v * v;
    #pragma unroll
    for (int off = 32; off > 0; off >>= 1) {
        s  += __shfl_down(s,  off, 64);
        s2 += __shfl_down(s2, off, 64);
    }
    __shared__ float ps[4], ps2[4];
    int wid = tid >> 6;
    if ((tid & 63) == 0) { ps[wid] = s; ps2[wid] = s2; }
    __syncthreads();
    float ts  = ps[0] + ps[1] + ps[2] + ps[3];
    float ts2 = ps2[0] + ps2[1] + ps2[2] + ps2[3];
    float mu  = ts * (1.0f / D_);
    float var = ts2 * (1.0f / D_) - mu * mu;
    float r = rsqrtf(var + EPS_);
    float o = (v - mu) * r * g[tid] + be[tid];
    if (BF16OUT) ((unsigned short*)out)[(size_t)row * D_ + tid] = f2bf(o);
    else         ((float*)out)[(size_t)row * D_ + tid] = o;
}

// ---------------- adj -> bitmask (1 bit per edge) ----------------
__global__ __launch_bounds__(256) void pack_adj(const int* __restrict__ adj,
        unsigned long long* __restrict__ mask) {
    size_t i = (size_t)blockIdx.x * 256 + threadIdx.x;
    unsigned long long bm = __ballot(adj[i] != 0);
    if ((threadIdx.x & 63) == 0) mask[i >> 6] = bm;
}

// ---------------- weight convert + transpose: W[K][Nc] f32 -> Wt[Nc][K] bf16 -
__global__ __launch_bounds__(256) void transpose_w(const float* __restrict__ W,
        unsigned short* __restrict__ Wt, int K, int Nc) {
    __shared__ float t[32][33];
    int n0 = blockIdx.x * 32, k0 = blockIdx.y * 32;
    int tx = threadIdx.x & 31, ty = threadIdx.x >> 5;   // 32 x 8
    #pragma unroll
    for (int i = 0; i < 4; i++)
        t[ty + i * 8][tx] = W[(size_t)(k0 + ty + i * 8) * Nc + n0 + tx];
    __syncthreads();
    #pragma unroll
    for (int i = 0; i < 4; i++)
        Wt[(size_t)(n0 + ty + i * 8) * K + k0 + tx] = f2bf(t[tx][ty + i * 8]);
}

// ---------------- bf16 MFMA GEMM: C = A[M,K] @ Bt[Nc,K]^T + bias ------------
// Block tile = (MI*32) x (NI*32), 4 waves 2x2, BK=32, swizzled global_load_lds.
#define GM_HEAD 0   // scatter bf16 to q/k/v (B,H,N,HD); Nc=768 fused; q pre-scaled
#define GM_RES  1   // f32 out, + bias + res
#define GM_GELU 2   // bf16 out, gelu(acc+bias)

template<int MODE, int MI, int NI>
__global__ __launch_bounds__(256) void gemm_mfma(
        const unsigned short* __restrict__ A,
        const unsigned short* __restrict__ Bt,
        const float* __restrict__ bias, const float* __restrict__ bias2,
        const float* __restrict__ bias3, const float* __restrict__ res,
        void* __restrict__ Cout,
        unsigned short* __restrict__ q_out, unsigned short* __restrict__ k_out,
        unsigned short* __restrict__ v_out, int M, int Nc, int K) {
    constexpr int BM = MI * 32, BN = NI * 32;
    __shared__ __align__(16) unsigned short Abuf[BM * 32];
    __shared__ __align__(16) unsigned short Bbuf[BN * 32];
    int tid = threadIdx.x, w = tid >> 6, lane = tid & 63;
    int lr = lane & 15, lg = lane >> 4;
    int wy = w >> 1, wx = w & 1;
    int m0 = blockIdx.y * BM, n0 = blockIdx.x * BN;
    f32x4 acc[MI][NI] = {};

    int srow = lane >> 2;
    int schunk = lane & 3;

    for (int k0 = 0; k0 < K; k0 += 32) {
        __syncthreads();
        #pragma unroll
        for (int i = 0; i < BM / 64; i++) {
            int ar = i * 64 + w * 16 + srow;
            int ac = schunk ^ ((ar >> 1) & 3);
            async_copy16(A + (size_t)(m0 + ar) * K + k0 + ac * 8,
                         Abuf + (size_t)(i * 64 + w * 16) * 32);
        }
        #pragma unroll
        for (int i = 0; i < BN / 64; i++) {
            int br = i * 64 + w * 16 + srow;
            int bc = schunk ^ ((br >> 1) & 3);
            async_copy16(Bt + (size_t)(n0 + br) * K + k0 + bc * 8,
                         Bbuf + (size_t)(i * 64 + w * 16) * 32);
        }
        __syncthreads();

        short8 af[MI], bf[NI];
        #pragma unroll
        for (int mi = 0; mi < MI; mi++) {
            int r = wy * (MI * 16) + mi * 16 + lr;
            int c = lg ^ ((r >> 1) & 3);
            af[mi] = *(const short8*)&Abuf[r * 32 + c * 8];
        }
        #pragma unroll
        for (int ni = 0; ni < NI; ni++) {
            int r = wx * (NI * 16) + ni * 16 + lr;
            int c = lg ^ ((r >> 1) & 3);
            bf[ni] = *(const short8*)&Bbuf[r * 32 + c * 8];
        }
        #pragma unroll
        for (int mi = 0; mi < MI; mi++)
            #pragma unroll
            for (int ni = 0; ni < NI; ni++)
                acc[mi][ni] = __builtin_amdgcn_mfma_f32_16x16x32_bf16(
                        af[mi], bf[ni], acc[mi][ni], 0, 0, 0);
    }

    #pragma unroll
    for (int mi = 0; mi < MI; mi++) {
        #pragma unroll
        for (int r = 0; r < 4; r++) {
            int grow = m0 + wy * (MI * 16) + mi * 16 + lg * 4 + r;
            #pragma unroll
            for (int ni = 0; ni < NI; ni++) {
                int gcol = n0 + wx * (NI * 16) + ni * 16 + lr;
                float val = acc[mi][ni][r];
                if (MODE == GM_HEAD) {
                    int which = gcol >> 8, nn = gcol & 255;
                    const float* bp = which == 0 ? bias : (which == 1 ? bias2 : bias3);
                    val += bp[nn];
                    if (which == 0) val *= QSC;   // fold log2e/sqrt(HD) into Q
                    unsigned short* dst = which == 0 ? q_out : (which == 1 ? k_out : v_out);
                    int bb = grow >> 11, rr = grow & (N_ - 1);
                    int hh = nn >> 5, dd = nn & 31;
                    dst[((((size_t)bb * H_ + hh) * N_) + rr) * HD_ + dd] = f2bf(val);
                } else if (MODE == GM_RES) {
                    val += bias[gcol] + res[(size_t)grow * Nc + gcol];
                    ((float*)Cout)[(size_t)grow * Nc + gcol] = val;
                } else {
                    val += bias[gcol];
                    val = 0.5f * val * (1.0f + erff(val * 0.70710678118654752f));
                    ((unsigned short*)Cout)[(size_t)grow * Nc + gcol] = f2bf(val);
                }
            }
        }
    }
}

// ---------------- MFMA flash attention v3: swapped QK^T, KVBLK=128 ----------
// block = 4 waves, 64 q-rows of one (b,h). Lane holds P-slice for q = lane&15.
__global__ __launch_bounds__(256) void attn_mfma3(
        const unsigned short* __restrict__ q, const unsigned short* __restrict__ k,
        const unsigned short* __restrict__ v, const unsigned long long* __restrict__ mask,
        unsigned short* __restrict__ out) {
    __shared__ __align__(16) unsigned short Kb[KV_ * 32];    // K rows, chunk-swizzled
    __shared__ __align__(16) unsigned short Vt[32 * KPAD];   // V^T [d][k]
    __shared__ __align__(16) unsigned short Pl[64 * KPAD];   // per-wave 16 P rows
    int b = blockIdx.z, h = blockIdx.y;
    int q0 = blockIdx.x * 64;
    int tid = threadIdx.x, w = tid >> 6, lane = tid & 63;
    int lr = lane & 15, lg = lane >> 4;
    size_t bh = (size_t)(b * H_ + h);
    const unsigned short* qbp = q + bh * N_ * HD_;
    const unsigned short* kbp = k + bh * N_ * HD_;
    const unsigned short* vbp = v + bh * N_ * HD_;

    short8 qf = *(const short8*)&qbp[(size_t)(q0 + w * 16 + lr) * HD_ + lg * 8];
    const unsigned long long* mrow = mask + ((size_t)b * N_ + q0 + w * 16 + lr) * (N_ / 64);

    int swz = (lr & 3) ^ ((lr >> 2) & 3);      // K read chunk XOR
    // K staging: row sr = tid>>2, chunk sc = tid&3, inverse-swizzled source
    int sr = tid >> 2, sc = tid & 3;
    int ssw = (sr & 3) ^ ((sr >> 2) & 3);
    const unsigned short* ksrc = kbp + (size_t)sr * HD_ + (sc ^ ssw) * 8;
    unsigned short* kdst0 = Kb + (size_t)w * 16 * 32;
    unsigned short* kdst1 = Kb + (size_t)(64 + w * 16) * 32;
    // V staging: lane -> 2 consecutive k-rows, wave -> d-block of 8; b32 pair writes
    int vd0 = w * 8;
    const unsigned short* vsrc = vbp + (size_t)(2 * lane) * HD_ + vd0;

    f32x4 acc0 = {}, acc1 = {};
    f32x4 zero = {};
    float m_run = -1e4f, l_run = 0.f;

    for (int t = 0; t < N_ / KV_; t++) {
        int k0 = t * KV_;
        __syncthreads();
        short8 v0 = *(const short8*)(vsrc + (size_t)k0 * HD_);
        short8 v1 = *(const short8*)(vsrc + (size_t)k0 * HD_ + HD_);
        async_copy16(ksrc + (size_t)k0 * HD_, kdst0);
        async_copy16(ksrc + (size_t)(k0 + 64) * HD_, kdst1);
        ulonglong2 mk = *(const ulonglong2*)&mrow[2 * t];
        #pragma unroll
        for (int i = 0; i < 8; i++) {
            unsigned pr = ((unsigned)(unsigned short)v1[i] << 16) | (unsigned short)v0[i];
            *(unsigned*)&Vt[(vd0 + i) * KPAD + 2 * lane] = pr;
        }
        __syncthreads();

        // S^T = K @ Q^T : lane (lr=q, lg) gets s for k = j*16 + lg*4 + r
        f32x4 s[8];
        #pragma unroll
        for (int j = 0; j < 8; j++) {
            short8 kf = *(const short8*)&Kb[(j * 16 + lr) * 32 + ((lg ^ swz) * 8)];
            s[j] = __builtin_amdgcn_mfma_f32_16x16x32_bf16(kf, qf, zero, 0, 0, 0);
        }

        unsigned mlo[2] = { (unsigned)(mk.x >> (lg * 4)), (unsigned)(mk.y >> (lg * 4)) };
        unsigned mhi[2] = { (unsigned)(mk.x >> (lg * 4 + 32)), (unsigned)(mk.y >> (lg * 4 + 32)) };
        float bm = -1e30f;
        #pragma unroll
        for (int j = 0; j < 8; j++) {
            unsigned mw = (j & 2) ? mhi[j >> 2] : mlo[j >> 2];
            #pragma unroll
            for (int r = 0; r < 4; r++) {
                int bit = (mw >> ((j & 1) * 16 + r)) & 1;
                float sv = bit ? s[j][r] : -1e30f;
                s[j][r] = sv;
                bm = fmaxf(bm, sv);
            }
        }
        bm = fmaxf(bm, __shfl_xor(bm, 16, 64));
        bm = fmaxf(bm, __shfl_xor(bm, 32, 64));
        float nm = fmaxf(m_run, bm);
        if (__any(nm - m_run > 8.0f)) {          // defer-max (T13)
            float sc_ = exp2f(m_run - nm);
            m_run = nm;
            l_run *= sc_;
            #pragma unroll
            for (int r = 0; r < 4; r++) {
                float scr = __shfl(sc_, lg * 4 + r, 64);
                acc0[r] *= scr;
                acc1[r] *= scr;
            }
        }
        float ls = 0.f;
        #pragma unroll
        for (int j = 0; j < 8; j++)
            #pragma unroll
            for (int r = 0; r < 4; r++) {
                float pv = exp2f(s[j][r] - m_run);   // masked: exp2(-1e30) = +0
                s[j][r] = pv;
                ls += pv;
            }
        ls += __shfl_xor(ls, 16, 64);
        ls += __shfl_xor(ls, 32, 64);
        l_run += ls;

        // pack P -> wave-private LDS rows [q=lr][k], b64 writes of cvt_pk pairs
        unsigned pbase = (w * 16 + lr) * KPAD;
        #pragma unroll
        for (int j = 0; j < 8; j++) {
            uint2 pq;
            pq.x = pk_bf16(s[j][0], s[j][1]);
            pq.y = pk_bf16(s[j][2], s[j][3]);
            *(uint2*)&Pl[pbase + j * 16 + lg * 4] = pq;
        }
        #pragma unroll
        for (int kc = 0; kc < 4; kc++) {
            short8 pf  = *(const short8*)&Pl[pbase + kc * 32 + lg * 8];
            short8 vfA = *(const short8*)&Vt[lr * KPAD + kc * 32 + lg * 8];
            short8 vfB = *(const short8*)&Vt[(lr + 16) * KPAD + kc * 32 + lg * 8];
            acc0 = __builtin_amdgcn_mfma_f32_16x16x32_bf16(pf, vfA, acc0, 0, 0, 0);
            acc1 = __builtin_amdgcn_mfma_f32_16x16x32_bf16(pf, vfB, acc1, 0, 0, 0);
        }
    }

    float linv = (l_run > 0.f) ? 1.0f / l_run : 0.f;   // lane-space: q = lr
    #pragma unroll
    for (int r = 0; r < 4; r++) {
        float ir = __shfl(linv, lg * 4 + r, 64);
        int row = q0 + w * 16 + lg * 4 + r;
        unsigned short* op = out + ((size_t)(b * N_) + row) * D_ + h * HD_;
        op[lr]      = f2bf(acc0[r] * ir);
        op[lr + 16] = f2bf(acc1[r] * ir);
    }
}

// ---------------- Launch -----------------------------------------------------
extern "C" void kernel_launch(void* const* d_in, const int* in_sizes, int n_in,
                              void* d_out, int out_size, void* d_ws, size_t ws_size,
                              hipStream_t stream) {
    const float* x   = (const float*)d_in[0];
    const int*   adj = (const int*)d_in[1];
    const float* wq  = (const float*)d_in[2];
    const float* bq  = (const float*)d_in[3];
    const float* wk  = (const float*)d_in[4];
    const float* bk  = (const float*)d_in[5];
    const float* wv  = (const float*)d_in[6];
    const float* bv  = (const float*)d_in[7];
    const float* wo  = (const float*)d_in[8];
    const float* bo  = (const float*)d_in[9];
    const float* g1  = (const float*)d_in[10];
    const float* be1 = (const float*)d_in[11];
    const float* g2  = (const float*)d_in[12];
    const float* be2 = (const float*)d_in[13];
    const float* w1  = (const float*)d_in[14];
    const float* b1  = (const float*)d_in[15];
    const float* w2  = (const float*)d_in[16];
    const float* b2  = (const float*)d_in[17];
    float* out = (float*)d_out;
    char* base = (char*)d_ws;

    const size_t MB = (size_t)1 << 20;
    unsigned long long* mask = (unsigned long long*)(base);     // 2 MB
    unsigned short* xn     = (unsigned short*)(base + 2*MB);    // 4 MB
    unsigned short* qb     = (unsigned short*)(base + 6*MB);    // 4 MB
    unsigned short* kb     = (unsigned short*)(base + 10*MB);   // 4 MB
    unsigned short* vb     = (unsigned short*)(base + 14*MB);   // 4 MB
    unsigned short* ao     = (unsigned short*)(base + 18*MB);   // 4 MB
    float*          x2     = (float*)(base + 22*MB);            // 8 MB
    unsigned short* hn     = (unsigned short*)(base + 30*MB);   // 4 MB
    unsigned short* h1     = (unsigned short*)(base + 34*MB);   // 16 MB
    unsigned short* wqkvt  = (unsigned short*)(base + 50*MB);   // 384 KB
    unsigned short* wot    = (unsigned short*)(base + 50*MB + 394240);   // 128 KB
    unsigned short* w1t    = (unsigned short*)(base + 51*MB);   // 512 KB
    unsigned short* w2t    = (unsigned short*)(base + 51*MB + 524288);   // 512 KB

    pack_adj<<<(B_ * N_ * N_) / 256, 256, 0, stream>>>(adj, mask);
    transpose_w<<<dim3(8, 8),  256, 0, stream>>>(wq, wqkvt,            256, 256);
    transpose_w<<<dim3(8, 8),  256, 0, stream>>>(wk, wqkvt + 256*256,  256, 256);
    transpose_w<<<dim3(8, 8),  256, 0, stream>>>(wv, wqkvt + 512*256,  256, 256);
    transpose_w<<<dim3(8, 8),  256, 0, stream>>>(wo, wot,              256, 256);
    transpose_w<<<dim3(32, 8), 256, 0, stream>>>(w1, w1t,              256, 1024);
    transpose_w<<<dim3(8, 32), 256, 0, stream>>>(w2, w2t,              1024, 256);

    ln_kernel<1><<<M_, 256, 0, stream>>>(x, g1, be1, xn);
    gemm_mfma<GM_HEAD, 2, 4><<<dim3(6, 128), 256, 0, stream>>>(
        xn, wqkvt, bq, bk, bv, nullptr, nullptr, qb, kb, vb, M_, 768, 256);
    attn_mfma3<<<dim3(N_ / 64, H_, B_), 256, 0, stream>>>(qb, kb, vb, mask, ao);
    gemm_mfma<GM_RES, 2, 2><<<dim3(4, 128), 256, 0, stream>>>(
        ao, wot, bo, nullptr, nullptr, x, x2, nullptr, nullptr, nullptr, M_, 256, 256);
    ln_kernel<1><<<M_, 256, 0, stream>>>(x2, g2, be2, hn);
    gemm_mfma<GM_GELU, 2, 4><<<dim3(8, 128), 256, 0, stream>>>(
        hn, w1t, b1, nullptr, nullptr, nullptr, h1, nullptr, nullptr, nullptr, M_, 1024, 256);
    gemm_mfma<GM_RES, 2, 2><<<dim3(4, 128), 256, 0, stream>>>(
        h1, w2t, b2, nullptr, nullptr, x2, out, nullptr, nullptr, nullptr, M_, 256, 1024);
}

// Round 6
// 176.871 us; speedup vs baseline: 1.0737x; 1.0737x over previous
//
#include <hip/hip_runtime.h>
#include <hip/hip_bf16.h>
#include <math.h>

#define B_ 4
#define N_ 2048
#define D_ 256
#define H_ 8
#define HD_ 32
#define F_ 1024
#define M_ (B_*N_)
#define EPS_ 1e-5f
#define VSTR 72

typedef __attribute__((ext_vector_type(8))) short short8;
typedef __attribute__((ext_vector_type(4))) float f32x4;

// log2(e)/sqrt(32): folded into Q so softmax uses exp2 directly
#define QSC 0.2550565499f

__device__ inline unsigned short f2bf(float f) {
    union { float f; unsigned u; } x; x.f = f;
    unsigned r = x.u + 0x7fff + ((x.u >> 16) & 1);
    return (unsigned short)(r >> 16);
}

__device__ inline unsigned pk_bf16(float a, float b) {
    union { __hip_bfloat162 h; unsigned u; } c;
    c.h = __float22bfloat162_rn(float2{a, b});
    return c.u;
}

__device__ inline void async_copy16(const void* g, void* l) {
    __builtin_amdgcn_global_load_lds(
        (const __attribute__((address_space(1))) void*)g,
        (__attribute__((address_space(3))) void*)l, 16, 0, 0);
}

// ---------------- LayerNorm: one WAVE per row (float4, no block sync) -------
template<int BF16OUT>
__global__ __launch_bounds__(256) void ln_kernel(const float* __restrict__ x,
        const float* __restrict__ g, const float* __restrict__ be,
        void* __restrict__ out) {
    int w = threadIdx.x >> 6, lane = threadIdx.x & 63;
    int row = blockIdx.x * 4 + w;
    float4 v = *(const float4*)&x[(size_t)row * D_ + lane * 4];
    float s  = v.x + v.y + v.z + v.w;
    float s2 = v.x * v.x + v.y * v.y + v.z * v.z + v.w * v.w;
    #pragma unroll
    for (int off = 1; off < 64; off <<= 1) {
        s  += __shfl_xor(s,  off, 64);
        s2 += __shfl_xor(s2, off, 64);
    }
    float mu  = s * (1.0f / D_);
    float var = s2 * (1.0f / D_) - mu * mu;
    float r = rsqrtf(var + EPS_);
    float4 gv = *(const float4*)&g[lane * 4];
    float4 bv = *(const float4*)&be[lane * 4];
    float o0 = (v.x - mu) * r * gv.x + bv.x;
    float o1 = (v.y - mu) * r * gv.y + bv.y;
    float o2 = (v.z - mu) * r * gv.z + bv.z;
    float o3 = (v.w - mu) * r * gv.w + bv.w;
    if (BF16OUT) {
        ushort4 u;
        u.x = f2bf(o0); u.y = f2bf(o1); u.z = f2bf(o2); u.w = f2bf(o3);
        *(ushort4*)&((unsigned short*)out)[(size_t)row * D_ + lane * 4] = u;
    } else {
        float4 o; o.x = o0; o.y = o1; o.z = o2; o.w = o3;
        *(float4*)&((float*)out)[(size_t)row * D_ + lane * 4] = o;
    }
}

// ---------------- adj -> bitmask (1 bit per edge) ----------------
__global__ __launch_bounds__(256) void pack_adj(const int* __restrict__ adj,
        unsigned long long* __restrict__ mask) {
    size_t i = (size_t)blockIdx.x * 256 + threadIdx.x;
    unsigned long long bm = __ballot(adj[i] != 0);
    if ((threadIdx.x & 63) == 0) mask[i >> 6] = bm;
}

// ---------------- all weight transposes in ONE kernel -----------------------
__global__ __launch_bounds__(256) void transpose_all(
        const float* __restrict__ wq, const float* __restrict__ wk,
        const float* __restrict__ wv, const float* __restrict__ wo,
        const float* __restrict__ w1, const float* __restrict__ w2,
        unsigned short* __restrict__ wqkvt, unsigned short* __restrict__ wot,
        unsigned short* __restrict__ w1t, unsigned short* __restrict__ w2t) {
    __shared__ float t[32][33];
    int id = blockIdx.x;
    const float* W; unsigned short* Wt; int K, Nc, n0, k0;
    if (id < 256) {
        int m = id >> 6, l = id & 63;
        K = 256; Nc = 256; n0 = (l & 7) * 32; k0 = (l >> 3) * 32;
        W  = m == 0 ? wq : (m == 1 ? wk : (m == 2 ? wv : wo));
        Wt = m == 0 ? wqkvt : (m == 1 ? wqkvt + 65536 : (m == 2 ? wqkvt + 131072 : wot));
    } else if (id < 512) {
        int l = id - 256; K = 256; Nc = 1024; n0 = (l & 31) * 32; k0 = (l >> 5) * 32;
        W = w1; Wt = w1t;
    } else {
        int l = id - 512; K = 1024; Nc = 256; n0 = (l & 7) * 32; k0 = (l >> 3) * 32;
        W = w2; Wt = w2t;
    }
    int tx = threadIdx.x & 31, ty = threadIdx.x >> 5;   // 32 x 8
    #pragma unroll
    for (int i = 0; i < 4; i++)
        t[ty + i * 8][tx] = W[(size_t)(k0 + ty + i * 8) * Nc + n0 + tx];
    __syncthreads();
    #pragma unroll
    for (int i = 0; i < 4; i++)
        Wt[(size_t)(n0 + ty + i * 8) * K + k0 + tx] = f2bf(t[tx][ty + i * 8]);
}

// ---------------- bf16 MFMA GEMM, double-buffered, 1 barrier / K-step -------
#define GM_HEAD 0   // scatter bf16 to q/k/v (B,H,N,HD); Nc=768 fused; q pre-scaled
#define GM_RES  1   // f32 out, + bias + res
#define GM_GELU 2   // bf16 out, gelu(acc+bias)

template<int MODE, int MI, int NI>
__global__ __launch_bounds__(256) void gemm_mfma(
        const unsigned short* __restrict__ A,
        const unsigned short* __restrict__ Bt,
        const float* __restrict__ bias, const float* __restrict__ bias2,
        const float* __restrict__ bias3, const float* __restrict__ res,
        void* __restrict__ Cout,
        unsigned short* __restrict__ q_out, unsigned short* __restrict__ k_out,
        unsigned short* __restrict__ v_out, int M, int Nc, int K) {
    constexpr int BM = MI * 32, BN = NI * 32;
    __shared__ __align__(16) unsigned short Abuf[2][BM * 32];
    __shared__ __align__(16) unsigned short Bbuf[2][BN * 32];
    int tid = threadIdx.x, w = tid >> 6, lane = tid & 63;
    int lr = lane & 15, lg = lane >> 4;
    int wy = w >> 1, wx = w & 1;
    int m0 = blockIdx.y * BM, n0 = blockIdx.x * BN;
    f32x4 acc[MI][NI] = {};

    int srow = lane >> 2;
    int schunk = lane & 3;

    auto STAGE = [&](int k0, int bi) {
        #pragma unroll
        for (int i = 0; i < BM / 64; i++) {
            int ar = i * 64 + w * 16 + srow;
            int ac = schunk ^ ((ar >> 1) & 3);
            async_copy16(A + (size_t)(m0 + ar) * K + k0 + ac * 8,
                         &Abuf[bi][(i * 64 + w * 16) * 32]);
        }
        #pragma unroll
        for (int i = 0; i < BN / 64; i++) {
            int br = i * 64 + w * 16 + srow;
            int bc = schunk ^ ((br >> 1) & 3);
            async_copy16(Bt + (size_t)(n0 + br) * K + k0 + bc * 8,
                         &Bbuf[bi][(i * 64 + w * 16) * 32]);
        }
    };

    int nkt = K / 32;
    STAGE(0, 0);
    for (int kt = 0; kt < nkt; kt++) {
        __syncthreads();                    // buf[kt&1] staged (barrier drains vmcnt)
        int cur = kt & 1;
        if (kt + 1 < nkt) STAGE((kt + 1) * 32, cur ^ 1);

        short8 af[MI], bf[NI];
        #pragma unroll
        for (int mi = 0; mi < MI; mi++) {
            int r = wy * (MI * 16) + mi * 16 + lr;
            int c = lg ^ ((r >> 1) & 3);
            af[mi] = *(const short8*)&Abuf[cur][r * 32 + c * 8];
        }
        #pragma unroll
        for (int ni = 0; ni < NI; ni++) {
            int r = wx * (NI * 16) + ni * 16 + lr;
            int c = lg ^ ((r >> 1) & 3);
            bf[ni] = *(const short8*)&Bbuf[cur][r * 32 + c * 8];
        }
        #pragma unroll
        for (int mi = 0; mi < MI; mi++)
            #pragma unroll
            for (int ni = 0; ni < NI; ni++)
                acc[mi][ni] = __builtin_amdgcn_mfma_f32_16x16x32_bf16(
                        af[mi], bf[ni], acc[mi][ni], 0, 0, 0);
    }

    #pragma unroll
    for (int mi = 0; mi < MI; mi++) {
        #pragma unroll
        for (int r = 0; r < 4; r++) {
            int grow = m0 + wy * (MI * 16) + mi * 16 + lg * 4 + r;
            #pragma unroll
            for (int ni = 0; ni < NI; ni++) {
                int gcol = n0 + wx * (NI * 16) + ni * 16 + lr;
                float val = acc[mi][ni][r];
                if (MODE == GM_HEAD) {
                    int which = gcol >> 8, nn = gcol & 255;
                    const float* bp = which == 0 ? bias : (which == 1 ? bias2 : bias3);
                    val += bp[nn];
                    if (which == 0) val *= QSC;   // fold log2e/sqrt(HD) into Q
                    unsigned short* dst = which == 0 ? q_out : (which == 1 ? k_out : v_out);
                    int bb = grow >> 11, rr = grow & (N_ - 1);
                    int hh = nn >> 5, dd = nn & 31;
                    dst[((((size_t)bb * H_ + hh) * N_) + rr) * HD_ + dd] = f2bf(val);
                } else if (MODE == GM_RES) {
                    val += bias[gcol] + res[(size_t)grow * Nc + gcol];
                    ((float*)Cout)[(size_t)grow * Nc + gcol] = val;
                } else {
                    val += bias[gcol];
                    val = 0.5f * val * (1.0f + erff(val * 0.70710678118654752f));
                    ((unsigned short*)Cout)[(size_t)grow * Nc + gcol] = f2bf(val);
                }
            }
        }
    }
}

// ---------------- MFMA flash attention v6 -----------------------------------
// 2 waves / 32 q-rows per block (2048 blocks), KVBLK=64, double-buffered K/V,
// one barrier per tile; swapped QK^T, exp2 softmax, defer-max.
__global__ __launch_bounds__(128) void attn_mfma4(
        const unsigned short* __restrict__ q, const unsigned short* __restrict__ k,
        const unsigned short* __restrict__ v, const unsigned long long* __restrict__ mask,
        unsigned short* __restrict__ out) {
    __shared__ __align__(16) unsigned short Kb[2][64 * 32];   // K rows, chunk-swizzled
    __shared__ __align__(16) unsigned short Vt[2][32 * VSTR]; // V^T [d][k]
    __shared__ __align__(16) unsigned short Pl[32 * VSTR];    // per-wave 16 P rows
    int b = blockIdx.z, h = blockIdx.y;
    int q0 = blockIdx.x * 32;
    int tid = threadIdx.x, w = tid >> 6, lane = tid & 63;
    int lr = lane & 15, lg = lane >> 4;
    size_t bh = (size_t)(b * H_ + h);
    const unsigned short* qbp = q + bh * N_ * HD_;
    const unsigned short* kbp = k + bh * N_ * HD_;
    const unsigned short* vbp = v + bh * N_ * HD_;

    short8 qf = *(const short8*)&qbp[(size_t)(q0 + w * 16 + lr) * HD_ + lg * 8];
    const unsigned long long* mrow = mask + ((size_t)b * N_ + q0 + w * 16 + lr) * (N_ / 64);

    int swz = (lr & 3) ^ ((lr >> 2) & 3);      // K read chunk XOR
    int sr = lane >> 2, sc = lane & 3;         // K staging row/chunk within 16-row issue
    int ssw = (sr & 3) ^ ((sr >> 2) & 3);
    int vj = tid & 31, vd0 = (tid >> 5) * 8;   // V staging: rows {2vj,2vj+1}, d-block vd0
    const unsigned short* vsrc = vbp + (size_t)(2 * vj) * HD_ + vd0;

    f32x4 acc0 = {}, acc1 = {};
    f32x4 zero = {};
    float m_run = -1e4f, l_run = 0.f;
    const int NT = N_ / 64;

    // ---- prologue: stage tile 0 ----
    #pragma unroll
    for (int i = 0; i < 2; i++)
        async_copy16(kbp + (size_t)(w * 32 + i * 16 + sr) * HD_ + (sc ^ ssw) * 8,
                     &Kb[0][(w * 32 + i * 16) * 32]);
    {
        short8 v0p = *(const short8*)vsrc;
        short8 v1p = *(const short8*)(vsrc + HD_);
        #pragma unroll
        for (int i = 0; i < 8; i++) {
            unsigned pr = ((unsigned)(unsigned short)v1p[i] << 16) | (unsigned short)v0p[i];
            *(unsigned*)&Vt[0][(vd0 + i) * VSTR + 2 * vj] = pr;
        }
    }
    unsigned long long mk_cur = mrow[0], mk_next = 0;
    short8 v0n = {}, v1n = {};

    for (int t = 0; t < NT; t++) {
        __syncthreads();                        // tile t staged (drains vmcnt+lgkm)
        int cur = t & 1;
        if (t + 1 < NT) {                       // issue next tile's loads (fly under compute)
            int k0n = (t + 1) * 64;
            #pragma unroll
            for (int i = 0; i < 2; i++)
                async_copy16(kbp + (size_t)(k0n + w * 32 + i * 16 + sr) * HD_ + (sc ^ ssw) * 8,
                             &Kb[cur ^ 1][(w * 32 + i * 16) * 32]);
            v0n = *(const short8*)(vsrc + (size_t)k0n * HD_);
            v1n = *(const short8*)(vsrc + (size_t)k0n * HD_ + HD_);
            mk_next = mrow[t + 1];
        }

        // S^T = K @ Q^T : lane (lr=q, lg) gets s for k = j*16 + lg*4 + r
        f32x4 s[4];
        #pragma unroll
        for (int j = 0; j < 4; j++) {
            short8 kf = *(const short8*)&Kb[cur][(j * 16 + lr) * 32 + ((lg ^ swz) * 8)];
            s[j] = __builtin_amdgcn_mfma_f32_16x16x32_bf16(kf, qf, zero, 0, 0, 0);
        }

        unsigned mlo = (unsigned)(mk_cur >> (lg * 4));
        unsigned mhi = (unsigned)(mk_cur >> (lg * 4 + 32));
        float bm = -1e30f;
        #pragma unroll
        for (int j = 0; j < 4; j++) {
            unsigned mw = (j & 2) ? mhi : mlo;
            #pragma unroll
            for (int r = 0; r < 4; r++) {
                int bit = (mw >> ((j & 1) * 16 + r)) & 1;
                float sv = bit ? s[j][r] : -1e30f;
                s[j][r] = sv;
                bm = fmaxf(bm, sv);
            }
        }
        bm = fmaxf(bm, __shfl_xor(bm, 16, 64));
        bm = fmaxf(bm, __shfl_xor(bm, 32, 64));
        float nm = fmaxf(m_run, bm);
        if (__any(nm - m_run > 8.0f)) {          // defer-max (T13)
            float sc_ = exp2f(m_run - nm);
            m_run = nm;
            l_run *= sc_;
            #pragma unroll
            for (int r = 0; r < 4; r++) {
                float scr = __shfl(sc_, lg * 4 + r, 64);
                acc0[r] *= scr;
                acc1[r] *= scr;
            }
        }
        float ls = 0.f;
        #pragma unroll
        for (int j = 0; j < 4; j++)
            #pragma unroll
            for (int r = 0; r < 4; r++) {
                float pv = exp2f(s[j][r] - m_run);   // masked: exp2(-inf) = +0
                s[j][r] = pv;
                ls += pv;
            }
        ls += __shfl_xor(ls, 16, 64);
        ls += __shfl_xor(ls, 32, 64);
        l_run += ls;

        // pack P -> wave-private LDS rows [q=lr][k], b64 writes of cvt_pk pairs
        unsigned pbase = (w * 16 + lr) * VSTR;
        #pragma unroll
        for (int j = 0; j < 4; j++) {
            uint2 pq;
            pq.x = pk_bf16(s[j][0], s[j][1]);
            pq.y = pk_bf16(s[j][2], s[j][3]);
            *(uint2*)&Pl[pbase + j * 16 + lg * 4] = pq;
        }
        #pragma unroll
        for (int kc = 0; kc < 2; kc++) {
            short8 pf  = *(const short8*)&Pl[pbase + kc * 32 + lg * 8];
            short8 vfA = *(const short8*)&Vt[cur][lr * VSTR + kc * 32 + lg * 8];
            short8 vfB = *(const short8*)&Vt[cur][(lr + 16) * VSTR + kc * 32 + lg * 8];
            acc0 = __builtin_amdgcn_mfma_f32_16x16x32_bf16(pf, vfA, acc0, 0, 0, 0);
            acc1 = __builtin_amdgcn_mfma_f32_16x16x32_bf16(pf, vfB, acc1, 0, 0, 0);
        }

        if (t + 1 < NT) {                       // late V write: loads landed during compute
            #pragma unroll
            for (int i = 0; i < 8; i++) {
                unsigned pr = ((unsigned)(unsigned short)v1n[i] << 16) | (unsigned short)v0n[i];
                *(unsigned*)&Vt[cur ^ 1][(vd0 + i) * VSTR + 2 * vj] = pr;
            }
        }
        mk_cur = mk_next;
    }

    float linv = (l_run > 0.f) ? 1.0f / l_run : 0.f;   // lane-space: q = lr
    #pragma unroll
    for (int r = 0; r < 4; r++) {
        float ir = __shfl(linv, lg * 4 + r, 64);
        int row = q0 + w * 16 + lg * 4 + r;
        unsigned short* op = out + ((size_t)(b * N_) + row) * D_ + h * HD_;
        op[lr]      = f2bf(acc0[r] * ir);
        op[lr + 16] = f2bf(acc1[r] * ir);
    }
}

// ---------------- Launch -----------------------------------------------------
extern "C" void kernel_launch(void* const* d_in, const int* in_sizes, int n_in,
                              void* d_out, int out_size, void* d_ws, size_t ws_size,
                              hipStream_t stream) {
    const float* x   = (const float*)d_in[0];
    const int*   adj = (const int*)d_in[1];
    const float* wq  = (const float*)d_in[2];
    const float* bq  = (const float*)d_in[3];
    const float* wk  = (const float*)d_in[4];
    const float* bk  = (const float*)d_in[5];
    const float* wv  = (const float*)d_in[6];
    const float* bv  = (const float*)d_in[7];
    const float* wo  = (const float*)d_in[8];
    const float* bo  = (const float*)d_in[9];
    const float* g1  = (const float*)d_in[10];
    const float* be1 = (const float*)d_in[11];
    const float* g2  = (const float*)d_in[12];
    const float* be2 = (const float*)d_in[13];
    const float* w1  = (const float*)d_in[14];
    const float* b1  = (const float*)d_in[15];
    const float* w2  = (const float*)d_in[16];
    const float* b2  = (const float*)d_in[17];
    float* out = (float*)d_out;
    char* base = (char*)d_ws;

    const size_t MB = (size_t)1 << 20;
    unsigned long long* mask = (unsigned long long*)(base);     // 2 MB
    unsigned short* xn     = (unsigned short*)(base + 2*MB);    // 4 MB
    unsigned short* qb     = (unsigned short*)(base + 6*MB);    // 4 MB
    unsigned short* kb     = (unsigned short*)(base + 10*MB);   // 4 MB
    unsigned short* vb     = (unsigned short*)(base + 14*MB);   // 4 MB
    unsigned short* ao     = (unsigned short*)(base + 18*MB);   // 4 MB
    float*          x2     = (float*)(base + 22*MB);            // 8 MB
    unsigned short* hn     = (unsigned short*)(base + 30*MB);   // 4 MB
    unsigned short* h1     = (unsigned short*)(base + 34*MB);   // 16 MB
    unsigned short* wqkvt  = (unsigned short*)(base + 50*MB);   // 384 KB
    unsigned short* wot    = (unsigned short*)(base + 50*MB + 394240);   // 128 KB
    unsigned short* w1t    = (unsigned short*)(base + 51*MB);   // 512 KB
    unsigned short* w2t    = (unsigned short*)(base + 51*MB + 524288);   // 512 KB

    pack_adj<<<(B_ * N_ * N_) / 256, 256, 0, stream>>>(adj, mask);
    transpose_all<<<768, 256, 0, stream>>>(wq, wk, wv, wo, w1, w2, wqkvt, wot, w1t, w2t);

    ln_kernel<1><<<M_ / 4, 256, 0, stream>>>(x, g1, be1, xn);
    gemm_mfma<GM_HEAD, 2, 4><<<dim3(6, 128), 256, 0, stream>>>(
        xn, wqkvt, bq, bk, bv, nullptr, nullptr, qb, kb, vb, M_, 768, 256);
    attn_mfma4<<<dim3(N_ / 32, H_, B_), 128, 0, stream>>>(qb, kb, vb, mask, ao);
    gemm_mfma<GM_RES, 2, 2><<<dim3(4, 128), 256, 0, stream>>>(
        ao, wot, bo, nullptr, nullptr, x, x2, nullptr, nullptr, nullptr, M_, 256, 256);
    ln_kernel<1><<<M_ / 4, 256, 0, stream>>>(x2, g2, be2, hn);
    gemm_mfma<GM_GELU, 2, 4><<<dim3(8, 128), 256, 0, stream>>>(
        hn, w1t, b1, nullptr, nullptr, nullptr, h1, nullptr, nullptr, nullptr, M_, 1024, 256);
    gemm_mfma<GM_RES, 2, 2><<<dim3(4, 128), 256, 0, stream>>>(
        h1, w2t, b2, nullptr, nullptr, x2, out, nullptr, nullptr, nullptr, M_, 256, 1024);
}

// Round 7
// 167.899 us; speedup vs baseline: 1.1311x; 1.0534x over previous
//
#include <hip/hip_runtime.h>
#include <hip/hip_bf16.h>
#include <math.h>

#define B_ 4
#define N_ 2048
#define D_ 256
#define H_ 8
#define HD_ 32
#define F_ 1024
#define M_ (B_*N_)
#define EPS_ 1e-5f
#define VSTR 72

typedef __attribute__((ext_vector_type(8))) short short8;
typedef __attribute__((ext_vector_type(4))) float f32x4;

// log2(e)/sqrt(32): folded into Q so softmax uses exp2 directly
#define QSC 0.2550565499f

__device__ inline unsigned short f2bf(float f) {
    union { float f; unsigned u; } x; x.f = f;
    unsigned r = x.u + 0x7fff + ((x.u >> 16) & 1);
    return (unsigned short)(r >> 16);
}

__device__ inline unsigned pk_bf16(float a, float b) {
    union { __hip_bfloat162 h; unsigned u; } c;
    c.h = __float22bfloat162_rn(float2{a, b});
    return c.u;
}

__device__ inline void async_copy16(const void* g, void* l) {
    __builtin_amdgcn_global_load_lds(
        (const __attribute__((address_space(1))) void*)g,
        (__attribute__((address_space(3))) void*)l, 16, 0, 0);
}

// ---------------- LayerNorm: one WAVE per row (float4, no block sync) -------
template<int BF16OUT>
__global__ __launch_bounds__(256) void ln_kernel(const float* __restrict__ x,
        const float* __restrict__ g, const float* __restrict__ be,
        void* __restrict__ out) {
    int w = threadIdx.x >> 6, lane = threadIdx.x & 63;
    int row = blockIdx.x * 4 + w;
    float4 v = *(const float4*)&x[(size_t)row * D_ + lane * 4];
    float s  = v.x + v.y + v.z + v.w;
    float s2 = v.x * v.x + v.y * v.y + v.z * v.z + v.w * v.w;
    #pragma unroll
    for (int off = 1; off < 64; off <<= 1) {
        s  += __shfl_xor(s,  off, 64);
        s2 += __shfl_xor(s2, off, 64);
    }
    float mu  = s * (1.0f / D_);
    float var = s2 * (1.0f / D_) - mu * mu;
    float r = rsqrtf(var + EPS_);
    float4 gv = *(const float4*)&g[lane * 4];
    float4 bv = *(const float4*)&be[lane * 4];
    float o0 = (v.x - mu) * r * gv.x + bv.x;
    float o1 = (v.y - mu) * r * gv.y + bv.y;
    float o2 = (v.z - mu) * r * gv.z + bv.z;
    float o3 = (v.w - mu) * r * gv.w + bv.w;
    if (BF16OUT) {
        ushort4 u;
        u.x = f2bf(o0); u.y = f2bf(o1); u.z = f2bf(o2); u.w = f2bf(o3);
        *(ushort4*)&((unsigned short*)out)[(size_t)row * D_ + lane * 4] = u;
    } else {
        float4 o; o.x = o0; o.y = o1; o.z = o2; o.w = o3;
        *(float4*)&((float*)out)[(size_t)row * D_ + lane * 4] = o;
    }
}

// ---------------- adj -> bitmask (1 bit per edge) ----------------
__global__ __launch_bounds__(256) void pack_adj(const int* __restrict__ adj,
        unsigned long long* __restrict__ mask) {
    size_t i = (size_t)blockIdx.x * 256 + threadIdx.x;
    unsigned long long bm = __ballot(adj[i] != 0);
    if ((threadIdx.x & 63) == 0) mask[i >> 6] = bm;
}

// ---------------- all weight transposes in ONE kernel -----------------------
__global__ __launch_bounds__(256) void transpose_all(
        const float* __restrict__ wq, const float* __restrict__ wk,
        const float* __restrict__ wv, const float* __restrict__ wo,
        const float* __restrict__ w1, const float* __restrict__ w2,
        unsigned short* __restrict__ wqkvt, unsigned short* __restrict__ wot,
        unsigned short* __restrict__ w1t, unsigned short* __restrict__ w2t) {
    __shared__ float t[32][33];
    int id = blockIdx.x;
    const float* W; unsigned short* Wt; int K, Nc, n0, k0;
    if (id < 256) {
        int m = id >> 6, l = id & 63;
        K = 256; Nc = 256; n0 = (l & 7) * 32; k0 = (l >> 3) * 32;
        W  = m == 0 ? wq : (m == 1 ? wk : (m == 2 ? wv : wo));
        Wt = m == 0 ? wqkvt : (m == 1 ? wqkvt + 65536 : (m == 2 ? wqkvt + 131072 : wot));
    } else if (id < 512) {
        int l = id - 256; K = 256; Nc = 1024; n0 = (l & 31) * 32; k0 = (l >> 5) * 32;
        W = w1; Wt = w1t;
    } else {
        int l = id - 512; K = 1024; Nc = 256; n0 = (l & 7) * 32; k0 = (l >> 3) * 32;
        W = w2; Wt = w2t;
    }
    int tx = threadIdx.x & 31, ty = threadIdx.x >> 5;   // 32 x 8
    #pragma unroll
    for (int i = 0; i < 4; i++)
        t[ty + i * 8][tx] = W[(size_t)(k0 + ty + i * 8) * Nc + n0 + tx];
    __syncthreads();
    #pragma unroll
    for (int i = 0; i < 4; i++)
        Wt[(size_t)(n0 + ty + i * 8) * K + k0 + tx] = f2bf(t[tx][ty + i * 8]);
}

// ---------------- bf16 MFMA GEMM, double-buffered, 1 barrier / K-step -------
#define GM_HEAD 0   // scatter bf16 to q/k/v (B,H,N,HD); Nc=768 fused; q pre-scaled
#define GM_RES  1   // f32 out, + bias + res
#define GM_GELU 2   // bf16 out, gelu(acc+bias)

template<int MODE, int MI, int NI>
__global__ __launch_bounds__(256) void gemm_mfma(
        const unsigned short* __restrict__ A,
        const unsigned short* __restrict__ Bt,
        const float* __restrict__ bias, const float* __restrict__ bias2,
        const float* __restrict__ bias3, const float* __restrict__ res,
        void* __restrict__ Cout,
        unsigned short* __restrict__ q_out, unsigned short* __restrict__ k_out,
        unsigned short* __restrict__ v_out, int M, int Nc, int K) {
    constexpr int BM = MI * 32, BN = NI * 32;
    __shared__ __align__(16) unsigned short Abuf[2][BM * 32];
    __shared__ __align__(16) unsigned short Bbuf[2][BN * 32];
    int tid = threadIdx.x, w = tid >> 6, lane = tid & 63;
    int lr = lane & 15, lg = lane >> 4;
    int wy = w >> 1, wx = w & 1;
    int m0 = blockIdx.y * BM, n0 = blockIdx.x * BN;
    f32x4 acc[MI][NI] = {};

    int srow = lane >> 2;
    int schunk = lane & 3;

    auto STAGE = [&](int k0, int bi) {
        #pragma unroll
        for (int i = 0; i < BM / 64; i++) {
            int ar = i * 64 + w * 16 + srow;
            int ac = schunk ^ ((ar >> 1) & 3);
            async_copy16(A + (size_t)(m0 + ar) * K + k0 + ac * 8,
                         &Abuf[bi][(i * 64 + w * 16) * 32]);
        }
        #pragma unroll
        for (int i = 0; i < BN / 64; i++) {
            int br = i * 64 + w * 16 + srow;
            int bc = schunk ^ ((br >> 1) & 3);
            async_copy16(Bt + (size_t)(n0 + br) * K + k0 + bc * 8,
                         &Bbuf[bi][(i * 64 + w * 16) * 32]);
        }
    };

    int nkt = K / 32;
    STAGE(0, 0);
    for (int kt = 0; kt < nkt; kt++) {
        __syncthreads();                    // buf[kt&1] staged (barrier drains vmcnt)
        int cur = kt & 1;
        if (kt + 1 < nkt) STAGE((kt + 1) * 32, cur ^ 1);

        short8 af[MI], bf[NI];
        #pragma unroll
        for (int mi = 0; mi < MI; mi++) {
            int r = wy * (MI * 16) + mi * 16 + lr;
            int c = lg ^ ((r >> 1) & 3);
            af[mi] = *(const short8*)&Abuf[cur][r * 32 + c * 8];
        }
        #pragma unroll
        for (int ni = 0; ni < NI; ni++) {
            int r = wx * (NI * 16) + ni * 16 + lr;
            int c = lg ^ ((r >> 1) & 3);
            bf[ni] = *(const short8*)&Bbuf[cur][r * 32 + c * 8];
        }
        #pragma unroll
        for (int mi = 0; mi < MI; mi++)
            #pragma unroll
            for (int ni = 0; ni < NI; ni++)
                acc[mi][ni] = __builtin_amdgcn_mfma_f32_16x16x32_bf16(
                        af[mi], bf[ni], acc[mi][ni], 0, 0, 0);
    }

    #pragma unroll
    for (int mi = 0; mi < MI; mi++) {
        #pragma unroll
        for (int r = 0; r < 4; r++) {
            int grow = m0 + wy * (MI * 16) + mi * 16 + lg * 4 + r;
            #pragma unroll
            for (int ni = 0; ni < NI; ni++) {
                int gcol = n0 + wx * (NI * 16) + ni * 16 + lr;
                float val = acc[mi][ni][r];
                if (MODE == GM_HEAD) {
                    int which = gcol >> 8, nn = gcol & 255;
                    const float* bp = which == 0 ? bias : (which == 1 ? bias2 : bias3);
                    val += bp[nn];
                    if (which == 0) val *= QSC;   // fold log2e/sqrt(HD) into Q
                    unsigned short* dst = which == 0 ? q_out : (which == 1 ? k_out : v_out);
                    int bb = grow >> 11, rr = grow & (N_ - 1);
                    int hh = nn >> 5, dd = nn & 31;
                    dst[((((size_t)bb * H_ + hh) * N_) + rr) * HD_ + dd] = f2bf(val);
                } else if (MODE == GM_RES) {
                    val += bias[gcol] + res[(size_t)grow * Nc + gcol];
                    ((float*)Cout)[(size_t)grow * Nc + gcol] = val;
                } else {
                    val += bias[gcol];
                    val = 0.5f * val * (1.0f + erff(val * 0.70710678118654752f));
                    ((unsigned short*)Cout)[(size_t)grow * Nc + gcol] = f2bf(val);
                }
            }
        }
    }
}

// ---------------- MFMA flash attention v7: max-free, split-K=2 --------------
// 4 waves / 64 q-rows, KVBLK=64 dbuf, 1 barrier/tile; swapped QK^T; no max
// tracking (scores are O(1) by construction; exp2 is safe in f32). Partial
// (acc,l) written f32; combine kernel adds halves and normalizes.
__global__ __launch_bounds__(256) void attn_mfma5(
        const unsigned short* __restrict__ q, const unsigned short* __restrict__ k,
        const unsigned short* __restrict__ v, const unsigned long long* __restrict__ mask,
        float* __restrict__ pacc, float* __restrict__ pl) {
    __shared__ __align__(16) unsigned short Kb[2][64 * 32];   // K rows, chunk-swizzled
    __shared__ __align__(16) unsigned short Vt[2][32 * VSTR]; // V^T [d][k]
    __shared__ __align__(16) unsigned short Ps[64 * VSTR];    // per-wave 16 P rows
    int b = blockIdx.z, h = blockIdx.y;
    int qblk = blockIdx.x >> 1, sk = blockIdx.x & 1;
    int q0 = qblk * 64;
    int tid = threadIdx.x, w = tid >> 6, lane = tid & 63;
    int lr = lane & 15, lg = lane >> 4;
    size_t bh = (size_t)(b * H_ + h);
    const unsigned short* qbp = q + bh * N_ * HD_;
    const unsigned short* kbp = k + bh * N_ * HD_;
    const unsigned short* vbp = v + bh * N_ * HD_;
    float* po = pacc + (size_t)sk * M_ * D_;
    float* plo = pl + (size_t)sk * M_ * H_;

    short8 qf = *(const short8*)&qbp[(size_t)(q0 + w * 16 + lr) * HD_ + lg * 8];
    const unsigned long long* mrow = mask + ((size_t)b * N_ + q0 + w * 16 + lr) * (N_ / 64);

    int swz = (lr & 3) ^ ((lr >> 2) & 3);          // K read chunk XOR
    int sr = lane >> 2, sc = lane & 3;             // K staging within wave's 16 rows
    int ssw = (sr & 3) ^ ((sr >> 2) & 3);
    const unsigned short* ksrc = kbp + (size_t)(w * 16 + sr) * HD_ + (sc ^ ssw) * 8;
    int va = tid & 31, vd = tid >> 5;              // V: rows {2va,2va+1}, d [vd*4,vd*4+4)
    const unsigned short* vsrc = vbp + (size_t)(2 * va) * HD_ + vd * 4;

    f32x4 acc0 = {}, acc1 = {};
    f32x4 zero = {};
    float l_lane = 0.f;
    const int NT2 = N_ / 64 / 2;
    int t0 = sk * NT2, t1 = t0 + NT2;

    // ---- prologue: stage tile t0 into buffer 0 ----
    {
        ushort4 v0p = *(const ushort4*)(vsrc + (size_t)t0 * 64 * HD_);
        ushort4 v1p = *(const ushort4*)(vsrc + (size_t)t0 * 64 * HD_ + HD_);
        async_copy16(ksrc + (size_t)t0 * 64 * HD_, &Kb[0][w * 16 * 32]);
        *(unsigned*)&Vt[0][(vd * 4 + 0) * VSTR + 2 * va] = ((unsigned)v1p.x << 16) | v0p.x;
        *(unsigned*)&Vt[0][(vd * 4 + 1) * VSTR + 2 * va] = ((unsigned)v1p.y << 16) | v0p.y;
        *(unsigned*)&Vt[0][(vd * 4 + 2) * VSTR + 2 * va] = ((unsigned)v1p.z << 16) | v0p.z;
        *(unsigned*)&Vt[0][(vd * 4 + 3) * VSTR + 2 * va] = ((unsigned)v1p.w << 16) | v0p.w;
    }
    unsigned long long mk_cur = mrow[t0], mk_next = 0;
    ushort4 v0n = {}, v1n = {};

    for (int t = t0; t < t1; t++) {
        __syncthreads();                        // tile t staged (drains vmcnt+lgkm)
        int cur = (t - t0) & 1;
        if (t + 1 < t1) {                       // prefetch t+1 (flies under compute)
            size_t koff = (size_t)(t + 1) * 64 * HD_;
            v0n = *(const ushort4*)(vsrc + koff);
            v1n = *(const ushort4*)(vsrc + koff + HD_);
            async_copy16(ksrc + koff, &Kb[cur ^ 1][w * 16 * 32]);
            mk_next = mrow[t + 1];
        }

        // S^T = K @ Q^T : lane (lr=q, lg) gets s for k = j*16 + lg*4 + r
        f32x4 s[4];
        #pragma unroll
        for (int j = 0; j < 4; j++) {
            short8 kf = *(const short8*)&Kb[cur][(j * 16 + lr) * 32 + ((lg ^ swz) * 8)];
            s[j] = __builtin_amdgcn_mfma_f32_16x16x32_bf16(kf, qf, zero, 0, 0, 0);
        }

        // max-free masked softmax numerator: p = bit ? exp2(s) : 0
        unsigned mlo = (unsigned)(mk_cur >> (lg * 4));
        unsigned mhi = (unsigned)(mk_cur >> (lg * 4 + 32));
        #pragma unroll
        for (int j = 0; j < 4; j++) {
            unsigned mw = (j & 2) ? mhi : mlo;
            #pragma unroll
            for (int r = 0; r < 4; r++) {
                int bit = (mw >> ((j & 1) * 16 + r)) & 1;
                float pv = exp2f(bit ? s[j][r] : -1e30f);   // exp2(-1e30) = +0
                s[j][r] = pv;
                l_lane += pv;
            }
        }

        // pack P -> wave-private LDS rows [q=lr][k], b64 writes of cvt_pk pairs
        unsigned pbase = (w * 16 + lr) * VSTR;
        #pragma unroll
        for (int j = 0; j < 4; j++) {
            uint2 pq;
            pq.x = pk_bf16(s[j][0], s[j][1]);
            pq.y = pk_bf16(s[j][2], s[j][3]);
            *(uint2*)&Ps[pbase + j * 16 + lg * 4] = pq;
        }
        #pragma unroll
        for (int kc = 0; kc < 2; kc++) {
            short8 pf  = *(const short8*)&Ps[pbase + kc * 32 + lg * 8];
            short8 vfA = *(const short8*)&Vt[cur][lr * VSTR + kc * 32 + lg * 8];
            short8 vfB = *(const short8*)&Vt[cur][(lr + 16) * VSTR + kc * 32 + lg * 8];
            acc0 = __builtin_amdgcn_mfma_f32_16x16x32_bf16(pf, vfA, acc0, 0, 0, 0);
            acc1 = __builtin_amdgcn_mfma_f32_16x16x32_bf16(pf, vfB, acc1, 0, 0, 0);
        }

        if (t + 1 < t1) {                       // late V write (loads landed under compute)
            *(unsigned*)&Vt[cur ^ 1][(vd * 4 + 0) * VSTR + 2 * va] = ((unsigned)v1n.x << 16) | v0n.x;
            *(unsigned*)&Vt[cur ^ 1][(vd * 4 + 1) * VSTR + 2 * va] = ((unsigned)v1n.y << 16) | v0n.y;
            *(unsigned*)&Vt[cur ^ 1][(vd * 4 + 2) * VSTR + 2 * va] = ((unsigned)v1n.z << 16) | v0n.z;
            *(unsigned*)&Vt[cur ^ 1][(vd * 4 + 3) * VSTR + 2 * va] = ((unsigned)v1n.w << 16) | v0n.w;
        }
        mk_cur = mk_next;
    }

    // per-q-row l (lane-space q = lr), then store partials
    float l = l_lane;
    l += __shfl_xor(l, 16, 64);
    l += __shfl_xor(l, 32, 64);
    if (lg == 0)
        plo[((size_t)b * N_ + q0 + w * 16 + lr) * H_ + h] = l;
    #pragma unroll
    for (int r = 0; r < 4; r++) {
        int row = q0 + w * 16 + lg * 4 + r;
        float* op = po + ((size_t)b * N_ + row) * D_ + h * HD_;
        op[lr]      = acc0[r];
        op[lr + 16] = acc1[r];
    }
}

// ---------------- combine split-K partials: ao = (p0+p1)/(l0+l1) ------------
__global__ __launch_bounds__(256) void combine_attn(
        const float* __restrict__ p0, const float* __restrict__ p1,
        const float* __restrict__ l0, const float* __restrict__ l1,
        unsigned short* __restrict__ ao) {
    int i8 = blockIdx.x * 256 + threadIdx.x;
    size_t base = (size_t)i8 * 8;
    int row = i8 >> 5;
    int h = (int)((base >> 5) & 7);
    float4 a0 = *(const float4*)&p0[base];
    float4 b0 = *(const float4*)&p0[base + 4];
    float4 a1 = *(const float4*)&p1[base];
    float4 b1 = *(const float4*)&p1[base + 4];
    float ls = l0[(size_t)row * H_ + h] + l1[(size_t)row * H_ + h];
    float inv = ls > 0.f ? 1.0f / ls : 0.f;
    ushort4 o0, o1;
    o0.x = f2bf((a0.x + a1.x) * inv); o0.y = f2bf((a0.y + a1.y) * inv);
    o0.z = f2bf((a0.z + a1.z) * inv); o0.w = f2bf((a0.w + a1.w) * inv);
    o1.x = f2bf((b0.x + b1.x) * inv); o1.y = f2bf((b0.y + b1.y) * inv);
    o1.z = f2bf((b0.z + b1.z) * inv); o1.w = f2bf((b0.w + b1.w) * inv);
    *(ushort4*)&ao[base] = o0;
    *(ushort4*)&ao[base + 4] = o1;
}

// ---------------- Launch -----------------------------------------------------
extern "C" void kernel_launch(void* const* d_in, const int* in_sizes, int n_in,
                              void* d_out, int out_size, void* d_ws, size_t ws_size,
                              hipStream_t stream) {
    const float* x   = (const float*)d_in[0];
    const int*   adj = (const int*)d_in[1];
    const float* wq  = (const float*)d_in[2];
    const float* bq  = (const float*)d_in[3];
    const float* wk  = (const float*)d_in[4];
    const float* bk  = (const float*)d_in[5];
    const float* wv  = (const float*)d_in[6];
    const float* bv  = (const float*)d_in[7];
    const float* wo  = (const float*)d_in[8];
    const float* bo  = (const float*)d_in[9];
    const float* g1  = (const float*)d_in[10];
    const float* be1 = (const float*)d_in[11];
    const float* g2  = (const float*)d_in[12];
    const float* be2 = (const float*)d_in[13];
    const float* w1  = (const float*)d_in[14];
    const float* b1  = (const float*)d_in[15];
    const float* w2  = (const float*)d_in[16];
    const float* b2  = (const float*)d_in[17];
    float* out = (float*)d_out;
    char* base = (char*)d_ws;

    const size_t MB = (size_t)1 << 20;
    unsigned long long* mask = (unsigned long long*)(base);     // 2 MB
    unsigned short* xn     = (unsigned short*)(base + 2*MB);    // 4 MB
    unsigned short* qb     = (unsigned short*)(base + 6*MB);    // 4 MB
    unsigned short* kb     = (unsigned short*)(base + 10*MB);   // 4 MB
    unsigned short* vb     = (unsigned short*)(base + 14*MB);   // 4 MB
    unsigned short* ao     = (unsigned short*)(base + 18*MB);   // 4 MB
    float*          x2     = (float*)(base + 22*MB);            // 8 MB
    unsigned short* hn     = (unsigned short*)(base + 30*MB);   // 4 MB
    unsigned short* h1     = (unsigned short*)(base + 34*MB);   // 16 MB (FFN)
    float*          pacc   = (float*)(base + 34*MB);            // 16 MB overlay (dead when h1 lives)
    float*          pl     = (float*)(base + 50*MB);            // 512 KB
    unsigned short* wqkvt  = (unsigned short*)(base + 51*MB);   // 384 KB
    unsigned short* wot    = (unsigned short*)(base + 51*MB + 394240);   // 128 KB
    unsigned short* w1t    = (unsigned short*)(base + 52*MB);   // 512 KB
    unsigned short* w2t    = (unsigned short*)(base + 52*MB + 524288);   // 512 KB

    pack_adj<<<(B_ * N_ * N_) / 256, 256, 0, stream>>>(adj, mask);
    transpose_all<<<768, 256, 0, stream>>>(wq, wk, wv, wo, w1, w2, wqkvt, wot, w1t, w2t);

    ln_kernel<1><<<M_ / 4, 256, 0, stream>>>(x, g1, be1, xn);
    gemm_mfma<GM_HEAD, 2, 4><<<dim3(6, 128), 256, 0, stream>>>(
        xn, wqkvt, bq, bk, bv, nullptr, nullptr, qb, kb, vb, M_, 768, 256);
    attn_mfma5<<<dim3(N_ / 32, H_, B_), 256, 0, stream>>>(qb, kb, vb, mask, pacc, pl);
    combine_attn<<<(M_ * D_) / (256 * 8), 256, 0, stream>>>(
        pacc, pacc + (size_t)M_ * D_, pl, pl + (size_t)M_ * H_, ao);
    gemm_mfma<GM_RES, 2, 2><<<dim3(4, 128), 256, 0, stream>>>(
        ao, wot, bo, nullptr, nullptr, x, x2, nullptr, nullptr, nullptr, M_, 256, 256);
    ln_kernel<1><<<M_ / 4, 256, 0, stream>>>(x2, g2, be2, hn);
    gemm_mfma<GM_GELU, 2, 4><<<dim3(8, 128), 256, 0, stream>>>(
        hn, w1t, b1, nullptr, nullptr, nullptr, h1, nullptr, nullptr, nullptr, M_, 1024, 256);
    gemm_mfma<GM_RES, 2, 2><<<dim3(4, 128), 256, 0, stream>>>(
        h1, w2t, b2, nullptr, nullptr, x2, out, nullptr, nullptr, nullptr, M_, 256, 1024);
}

// Round 8
// 167.879 us; speedup vs baseline: 1.1313x; 1.0001x over previous
//
#include <hip/hip_runtime.h>
#include <hip/hip_bf16.h>
#include <math.h>

#define B_ 4
#define N_ 2048
#define D_ 256
#define H_ 8
#define HD_ 32
#define F_ 1024
#define M_ (B_*N_)
#define EPS_ 1e-5f
#define VSTR 72

typedef __attribute__((ext_vector_type(8))) short short8;
typedef __attribute__((ext_vector_type(4))) float f32x4;

// log2(e)/sqrt(32): folded into Q so softmax uses exp2 directly
#define QSC 0.2550565499f

__device__ inline unsigned short f2bf(float f) {
    union { float f; unsigned u; } x; x.f = f;
    unsigned r = x.u + 0x7fff + ((x.u >> 16) & 1);
    return (unsigned short)(r >> 16);
}

__device__ inline unsigned pk_bf16(float a, float b) {
    union { __hip_bfloat162 h; unsigned u; } c;
    c.h = __float22bfloat162_rn(float2{a, b});
    return c.u;
}

__device__ inline void async_copy16(const void* g, void* l) {
    __builtin_amdgcn_global_load_lds(
        (const __attribute__((address_space(1))) void*)g,
        (__attribute__((address_space(3))) void*)l, 16, 0, 0);
}

// ---------------- LayerNorm body: one wave, 4 rows/block ---------------------
__device__ inline void ln_rows(const float* __restrict__ x,
        const float* __restrict__ g, const float* __restrict__ be,
        unsigned short* __restrict__ out, int blk) {
    int w = threadIdx.x >> 6, lane = threadIdx.x & 63;
    int row = blk * 4 + w;
    float4 v = *(const float4*)&x[(size_t)row * D_ + lane * 4];
    float s  = v.x + v.y + v.z + v.w;
    float s2 = v.x * v.x + v.y * v.y + v.z * v.z + v.w * v.w;
    #pragma unroll
    for (int off = 1; off < 64; off <<= 1) {
        s  += __shfl_xor(s,  off, 64);
        s2 += __shfl_xor(s2, off, 64);
    }
    float mu  = s * (1.0f / D_);
    float var = s2 * (1.0f / D_) - mu * mu;
    float r = rsqrtf(var + EPS_);
    float4 gv = *(const float4*)&g[lane * 4];
    float4 bv = *(const float4*)&be[lane * 4];
    ushort4 u;
    u.x = f2bf((v.x - mu) * r * gv.x + bv.x);
    u.y = f2bf((v.y - mu) * r * gv.y + bv.y);
    u.z = f2bf((v.z - mu) * r * gv.z + bv.z);
    u.w = f2bf((v.w - mu) * r * gv.w + bv.w);
    *(ushort4*)&out[(size_t)row * D_ + lane * 4] = u;
}

__global__ __launch_bounds__(256) void ln_kernel(const float* __restrict__ x,
        const float* __restrict__ g, const float* __restrict__ be,
        unsigned short* __restrict__ out) {
    ln_rows(x, g, be, out, blockIdx.x);
}

// ---------------- fused prep: pack_adj | weight transpose | LN1 --------------
// blocks [0,65536): pack adj bits; [65536,66304): transposes; [66304,68352): ln1
__global__ __launch_bounds__(256) void prep_kernel(
        const int* __restrict__ adj, unsigned long long* __restrict__ mask,
        const float* __restrict__ wq, const float* __restrict__ wk,
        const float* __restrict__ wv, const float* __restrict__ wo,
        const float* __restrict__ w1, const float* __restrict__ w2,
        unsigned short* __restrict__ wqkvt, unsigned short* __restrict__ wot,
        unsigned short* __restrict__ w1t, unsigned short* __restrict__ w2t,
        const float* __restrict__ x, const float* __restrict__ g1,
        const float* __restrict__ be1, unsigned short* __restrict__ xn) {
    __shared__ float t[32][33];
    int id = blockIdx.x;
    if (id < 65536) {
        size_t i = (size_t)id * 256 + threadIdx.x;
        unsigned long long bm = __ballot(adj[i] != 0);
        if ((threadIdx.x & 63) == 0) mask[i >> 6] = bm;
        return;
    }
    if (id >= 66304) {
        ln_rows(x, g1, be1, xn, id - 66304);
        return;
    }
    id -= 65536;
    const float* W; unsigned short* Wt; int K, Nc, n0, k0;
    if (id < 256) {
        int m = id >> 6, l = id & 63;
        K = 256; Nc = 256; n0 = (l & 7) * 32; k0 = (l >> 3) * 32;
        W  = m == 0 ? wq : (m == 1 ? wk : (m == 2 ? wv : wo));
        Wt = m == 0 ? wqkvt : (m == 1 ? wqkvt + 65536 : (m == 2 ? wqkvt + 131072 : wot));
    } else if (id < 512) {
        int l = id - 256; K = 256; Nc = 1024; n0 = (l & 31) * 32; k0 = (l >> 5) * 32;
        W = w1; Wt = w1t;
    } else {
        int l = id - 512; K = 1024; Nc = 256; n0 = (l & 7) * 32; k0 = (l >> 3) * 32;
        W = w2; Wt = w2t;
    }
    int tx = threadIdx.x & 31, ty = threadIdx.x >> 5;   // 32 x 8
    #pragma unroll
    for (int i = 0; i < 4; i++)
        t[ty + i * 8][tx] = W[(size_t)(k0 + ty + i * 8) * Nc + n0 + tx];
    __syncthreads();
    #pragma unroll
    for (int i = 0; i < 4; i++)
        Wt[(size_t)(n0 + ty + i * 8) * K + k0 + tx] = f2bf(t[tx][ty + i * 8]);
}

// ---------------- bf16 MFMA GEMM, double-buffered, 1 barrier / K-step -------
#define GM_HEAD 0   // scatter bf16 to q/k/v (B,H,N,HD); Nc=768 fused; q pre-scaled
#define GM_RES  1   // f32 out, + bias + res
#define GM_GELU 2   // bf16 out, gelu(acc+bias)

template<int MODE, int MI, int NI>
__global__ __launch_bounds__(256) void gemm_mfma(
        const unsigned short* __restrict__ A,
        const unsigned short* __restrict__ Bt,
        const float* __restrict__ bias, const float* __restrict__ bias2,
        const float* __restrict__ bias3, const float* __restrict__ res,
        void* __restrict__ Cout,
        unsigned short* __restrict__ q_out, unsigned short* __restrict__ k_out,
        unsigned short* __restrict__ v_out, int M, int Nc, int K) {
    constexpr int BM = MI * 32, BN = NI * 32;
    __shared__ __align__(16) unsigned short Abuf[2][BM * 32];
    __shared__ __align__(16) unsigned short Bbuf[2][BN * 32];
    int tid = threadIdx.x, w = tid >> 6, lane = tid & 63;
    int lr = lane & 15, lg = lane >> 4;
    int wy = w >> 1, wx = w & 1;
    int m0 = blockIdx.y * BM, n0 = blockIdx.x * BN;
    f32x4 acc[MI][NI] = {};

    int srow = lane >> 2;
    int schunk = lane & 3;

    auto STAGE = [&](int k0, int bi) {
        #pragma unroll
        for (int i = 0; i < BM / 64; i++) {
            int ar = i * 64 + w * 16 + srow;
            int ac = schunk ^ ((ar >> 1) & 3);
            async_copy16(A + (size_t)(m0 + ar) * K + k0 + ac * 8,
                         &Abuf[bi][(i * 64 + w * 16) * 32]);
        }
        #pragma unroll
        for (int i = 0; i < BN / 64; i++) {
            int br = i * 64 + w * 16 + srow;
            int bc = schunk ^ ((br >> 1) & 3);
            async_copy16(Bt + (size_t)(n0 + br) * K + k0 + bc * 8,
                         &Bbuf[bi][(i * 64 + w * 16) * 32]);
        }
    };

    int nkt = K / 32;
    STAGE(0, 0);
    for (int kt = 0; kt < nkt; kt++) {
        __syncthreads();                    // buf[kt&1] staged (barrier drains vmcnt)
        int cur = kt & 1;
        if (kt + 1 < nkt) STAGE((kt + 1) * 32, cur ^ 1);

        short8 af[MI], bf[NI];
        #pragma unroll
        for (int mi = 0; mi < MI; mi++) {
            int r = wy * (MI * 16) + mi * 16 + lr;
            int c = lg ^ ((r >> 1) & 3);
            af[mi] = *(const short8*)&Abuf[cur][r * 32 + c * 8];
        }
        #pragma unroll
        for (int ni = 0; ni < NI; ni++) {
            int r = wx * (NI * 16) + ni * 16 + lr;
            int c = lg ^ ((r >> 1) & 3);
            bf[ni] = *(const short8*)&Bbuf[cur][r * 32 + c * 8];
        }
        #pragma unroll
        for (int mi = 0; mi < MI; mi++)
            #pragma unroll
            for (int ni = 0; ni < NI; ni++)
                acc[mi][ni] = __builtin_amdgcn_mfma_f32_16x16x32_bf16(
                        af[mi], bf[ni], acc[mi][ni], 0, 0, 0);
    }

    #pragma unroll
    for (int mi = 0; mi < MI; mi++) {
        #pragma unroll
        for (int r = 0; r < 4; r++) {
            int grow = m0 + wy * (MI * 16) + mi * 16 + lg * 4 + r;
            #pragma unroll
            for (int ni = 0; ni < NI; ni++) {
                int gcol = n0 + wx * (NI * 16) + ni * 16 + lr;
                float val = acc[mi][ni][r];
                if (MODE == GM_HEAD) {
                    int which = gcol >> 8, nn = gcol & 255;
                    const float* bp = which == 0 ? bias : (which == 1 ? bias2 : bias3);
                    val += bp[nn];
                    if (which == 0) val *= QSC;   // fold log2e/sqrt(HD) into Q
                    unsigned short* dst = which == 0 ? q_out : (which == 1 ? k_out : v_out);
                    int bb = grow >> 11, rr = grow & (N_ - 1);
                    int hh = nn >> 5, dd = nn & 31;
                    dst[((((size_t)bb * H_ + hh) * N_) + rr) * HD_ + dd] = f2bf(val);
                } else if (MODE == GM_RES) {
                    val += bias[gcol] + res[(size_t)grow * Nc + gcol];
                    ((float*)Cout)[(size_t)grow * Nc + gcol] = val;
                } else {
                    val += bias[gcol];
                    val = 0.5f * val * (1.0f + erff(val * 0.70710678118654752f));
                    ((unsigned short*)Cout)[(size_t)grow * Nc + gcol] = f2bf(val);
                }
            }
        }
    }
}

// ---------------- MFMA flash attention v8: zero-shuffle P -------------------
// Max-free split-K=2 (v7) + key-permuted V staging so each lane's QK outputs
// ARE the PV A-fragment: physical key p=[kc|u|lg|r] -> V slot sigma=[kc|lg|u|r].
// P never touches LDS or another lane.
__global__ __launch_bounds__(256) void attn_mfma6(
        const unsigned short* __restrict__ q, const unsigned short* __restrict__ k,
        const unsigned short* __restrict__ v, const unsigned long long* __restrict__ mask,
        float* __restrict__ pacc, float* __restrict__ pl) {
    __shared__ __align__(16) unsigned short Kb[2][64 * 32];   // K rows, chunk-swizzled
    __shared__ __align__(16) unsigned short Vt[2][32 * VSTR]; // V^T [d][sigma]
    int b = blockIdx.z, h = blockIdx.y;
    int qblk = blockIdx.x >> 1, sk = blockIdx.x & 1;
    int q0 = qblk * 64;
    int tid = threadIdx.x, w = tid >> 6, lane = tid & 63;
    int lr = lane & 15, lg = lane >> 4;
    size_t bh = (size_t)(b * H_ + h);
    const unsigned short* qbp = q + bh * N_ * HD_;
    const unsigned short* kbp = k + bh * N_ * HD_;
    const unsigned short* vbp = v + bh * N_ * HD_;
    float* po = pacc + (size_t)sk * M_ * D_;
    float* plo = pl + (size_t)sk * M_ * H_;

    short8 qf = *(const short8*)&qbp[(size_t)(q0 + w * 16 + lr) * HD_ + lg * 8];
    const unsigned long long* mrow = mask + ((size_t)b * N_ + q0 + w * 16 + lr) * (N_ / 64);

    int swz = (lr & 3) ^ ((lr >> 2) & 3);          // K read chunk XOR
    int sr = lane >> 2, sc = lane & 3;             // K staging within wave's 16 rows
    int ssw = (sr & 3) ^ ((sr >> 2) & 3);
    const unsigned short* ksrc = kbp + (size_t)(w * 16 + sr) * HD_ + (sc ^ ssw) * 8;
    int va = tid & 31, vd = tid >> 5;              // V: phys rows {2va,2va+1}, d [vd*4,+4)
    const unsigned short* vsrc = vbp + (size_t)(2 * va) * HD_ + vd * 4;
    int p2 = 2 * va;                               // sigma: [kc|u|lg|r] -> [kc|lg|u|r]
    int sig = (p2 & 35) | ((p2 & 12) << 1) | ((p2 & 16) >> 2);

    f32x4 acc0 = {}, acc1 = {};
    f32x4 zero = {};
    float l_lane = 0.f;
    const int NT2 = N_ / 64 / 2;
    int t0 = sk * NT2, t1 = t0 + NT2;

    // ---- prologue: stage tile t0 into buffer 0 ----
    {
        ushort4 v0p = *(const ushort4*)(vsrc + (size_t)t0 * 64 * HD_);
        ushort4 v1p = *(const ushort4*)(vsrc + (size_t)t0 * 64 * HD_ + HD_);
        async_copy16(ksrc + (size_t)t0 * 64 * HD_, &Kb[0][w * 16 * 32]);
        *(unsigned*)&Vt[0][(vd * 4 + 0) * VSTR + sig] = ((unsigned)v1p.x << 16) | v0p.x;
        *(unsigned*)&Vt[0][(vd * 4 + 1) * VSTR + sig] = ((unsigned)v1p.y << 16) | v0p.y;
        *(unsigned*)&Vt[0][(vd * 4 + 2) * VSTR + sig] = ((unsigned)v1p.z << 16) | v0p.z;
        *(unsigned*)&Vt[0][(vd * 4 + 3) * VSTR + sig] = ((unsigned)v1p.w << 16) | v0p.w;
    }
    unsigned long long mk_cur = mrow[t0], mk_next = 0;
    ushort4 v0n = {}, v1n = {};

    for (int t = t0; t < t1; t++) {
        __syncthreads();                        // tile t staged (drains vmcnt+lgkm)
        int cur = (t - t0) & 1;
        if (t + 1 < t1) {                       // prefetch t+1 (flies under compute)
            size_t koff = (size_t)(t + 1) * 64 * HD_;
            v0n = *(const ushort4*)(vsrc + koff);
            v1n = *(const ushort4*)(vsrc + koff + HD_);
            async_copy16(ksrc + koff, &Kb[cur ^ 1][w * 16 * 32]);
            mk_next = mrow[t + 1];
        }

        // S^T = K @ Q^T : lane (lr=q, lg) gets s for phys k = j*16 + lg*4 + r
        f32x4 s[4];
        #pragma unroll
        for (int j = 0; j < 4; j++) {
            short8 kf = *(const short8*)&Kb[cur][(j * 16 + lr) * 32 + ((lg ^ swz) * 8)];
            s[j] = __builtin_amdgcn_mfma_f32_16x16x32_bf16(kf, qf, zero, 0, 0, 0);
        }

        // max-free masked softmax numerator: p = bit ? exp2(s) : 0
        unsigned mlo = (unsigned)(mk_cur >> (lg * 4));
        unsigned mhi = (unsigned)(mk_cur >> (lg * 4 + 32));
        #pragma unroll
        for (int j = 0; j < 4; j++) {
            unsigned mw = (j & 2) ? mhi : mlo;
            #pragma unroll
            for (int r = 0; r < 4; r++) {
                float ev = exp2f(s[j][r]);
                int bit = (mw >> ((j & 1) * 16 + r)) & 1;
                float pv = bit ? ev : 0.f;
                s[j][r] = pv;
                l_lane += pv;
            }
        }

        // P is already the PV A-fragment (key-permuted V): pack in-register
        union { short8 v8; unsigned u[4]; } pf0, pf1;
        pf0.u[0] = pk_bf16(s[0][0], s[0][1]); pf0.u[1] = pk_bf16(s[0][2], s[0][3]);
        pf0.u[2] = pk_bf16(s[1][0], s[1][1]); pf0.u[3] = pk_bf16(s[1][2], s[1][3]);
        pf1.u[0] = pk_bf16(s[2][0], s[2][1]); pf1.u[1] = pk_bf16(s[2][2], s[2][3]);
        pf1.u[2] = pk_bf16(s[3][0], s[3][1]); pf1.u[3] = pk_bf16(s[3][2], s[3][3]);

        short8 vfA0 = *(const short8*)&Vt[cur][lr * VSTR + lg * 8];
        short8 vfB0 = *(const short8*)&Vt[cur][(lr + 16) * VSTR + lg * 8];
        short8 vfA1 = *(const short8*)&Vt[cur][lr * VSTR + 32 + lg * 8];
        short8 vfB1 = *(const short8*)&Vt[cur][(lr + 16) * VSTR + 32 + lg * 8];
        acc0 = __builtin_amdgcn_mfma_f32_16x16x32_bf16(pf0.v8, vfA0, acc0, 0, 0, 0);
        acc1 = __builtin_amdgcn_mfma_f32_16x16x32_bf16(pf0.v8, vfB0, acc1, 0, 0, 0);
        acc0 = __builtin_amdgcn_mfma_f32_16x16x32_bf16(pf1.v8, vfA1, acc0, 0, 0, 0);
        acc1 = __builtin_amdgcn_mfma_f32_16x16x32_bf16(pf1.v8, vfB1, acc1, 0, 0, 0);

        if (t + 1 < t1) {                       // late V write (loads landed under compute)
            *(unsigned*)&Vt[cur ^ 1][(vd * 4 + 0) * VSTR + sig] = ((unsigned)v1n.x << 16) | v0n.x;
            *(unsigned*)&Vt[cur ^ 1][(vd * 4 + 1) * VSTR + sig] = ((unsigned)v1n.y << 16) | v0n.y;
            *(unsigned*)&Vt[cur ^ 1][(vd * 4 + 2) * VSTR + sig] = ((unsigned)v1n.z << 16) | v0n.z;
            *(unsigned*)&Vt[cur ^ 1][(vd * 4 + 3) * VSTR + sig] = ((unsigned)v1n.w << 16) | v0n.w;
        }
        mk_cur = mk_next;
    }

    // per-q-row l (lane-space q = lr), then store partials
    float l = l_lane;
    l += __shfl_xor(l, 16, 64);
    l += __shfl_xor(l, 32, 64);
    if (lg == 0)
        plo[((size_t)b * N_ + q0 + w * 16 + lr) * H_ + h] = l;
    #pragma unroll
    for (int r = 0; r < 4; r++) {
        int row = q0 + w * 16 + lg * 4 + r;
        float* op = po + ((size_t)b * N_ + row) * D_ + h * HD_;
        op[lr]      = acc0[r];
        op[lr + 16] = acc1[r];
    }
}

// ---------------- combine split-K partials: ao = (p0+p1)/(l0+l1) ------------
__global__ __launch_bounds__(256) void combine_attn(
        const float* __restrict__ p0, const float* __restrict__ p1,
        const float* __restrict__ l0, const float* __restrict__ l1,
        unsigned short* __restrict__ ao) {
    int i8 = blockIdx.x * 256 + threadIdx.x;
    size_t base = (size_t)i8 * 8;
    int row = i8 >> 5;
    int h = (int)((base >> 5) & 7);
    float4 a0 = *(const float4*)&p0[base];
    float4 b0 = *(const float4*)&p0[base + 4];
    float4 a1 = *(const float4*)&p1[base];
    float4 b1 = *(const float4*)&p1[base + 4];
    float ls = l0[(size_t)row * H_ + h] + l1[(size_t)row * H_ + h];
    float inv = ls > 0.f ? 1.0f / ls : 0.f;
    ushort4 o0, o1;
    o0.x = f2bf((a0.x + a1.x) * inv); o0.y = f2bf((a0.y + a1.y) * inv);
    o0.z = f2bf((a0.z + a1.z) * inv); o0.w = f2bf((a0.w + a1.w) * inv);
    o1.x = f2bf((b0.x + b1.x) * inv); o1.y = f2bf((b0.y + b1.y) * inv);
    o1.z = f2bf((b0.z + b1.z) * inv); o1.w = f2bf((b0.w + b1.w) * inv);
    *(ushort4*)&ao[base] = o0;
    *(ushort4*)&ao[base + 4] = o1;
}

// ---------------- Launch -----------------------------------------------------
extern "C" void kernel_launch(void* const* d_in, const int* in_sizes, int n_in,
                              void* d_out, int out_size, void* d_ws, size_t ws_size,
                              hipStream_t stream) {
    const float* x   = (const float*)d_in[0];
    const int*   adj = (const int*)d_in[1];
    const float* wq  = (const float*)d_in[2];
    const float* bq  = (const float*)d_in[3];
    const float* wk  = (const float*)d_in[4];
    const float* bk  = (const float*)d_in[5];
    const float* wv  = (const float*)d_in[6];
    const float* bv  = (const float*)d_in[7];
    const float* wo  = (const float*)d_in[8];
    const float* bo  = (const float*)d_in[9];
    const float* g1  = (const float*)d_in[10];
    const float* be1 = (const float*)d_in[11];
    const float* g2  = (const float*)d_in[12];
    const float* be2 = (const float*)d_in[13];
    const float* w1  = (const float*)d_in[14];
    const float* b1  = (const float*)d_in[15];
    const float* w2  = (const float*)d_in[16];
    const float* b2  = (const float*)d_in[17];
    float* out = (float*)d_out;
    char* base = (char*)d_ws;

    const size_t MB = (size_t)1 << 20;
    unsigned long long* mask = (unsigned long long*)(base);     // 2 MB
    unsigned short* xn     = (unsigned short*)(base + 2*MB);    // 4 MB
    unsigned short* qb     = (unsigned short*)(base + 6*MB);    // 4 MB
    unsigned short* kb     = (unsigned short*)(base + 10*MB);   // 4 MB
    unsigned short* vb     = (unsigned short*)(base + 14*MB);   // 4 MB
    unsigned short* ao     = (unsigned short*)(base + 18*MB);   // 4 MB
    float*          x2     = (float*)(base + 22*MB);            // 8 MB
    unsigned short* hn     = (unsigned short*)(base + 30*MB);   // 4 MB
    unsigned short* h1     = (unsigned short*)(base + 34*MB);   // 16 MB (FFN)
    float*          pacc   = (float*)(base + 34*MB);            // 16 MB overlay (dead when h1 lives)
    float*          pl     = (float*)(base + 50*MB);            // 512 KB
    unsigned short* wqkvt  = (unsigned short*)(base + 51*MB);   // 384 KB
    unsigned short* wot    = (unsigned short*)(base + 51*MB + 394240);   // 128 KB
    unsigned short* w1t    = (unsigned short*)(base + 52*MB);   // 512 KB
    unsigned short* w2t    = (unsigned short*)(base + 52*MB + 524288);   // 512 KB

    prep_kernel<<<65536 + 768 + 2048, 256, 0, stream>>>(
        adj, mask, wq, wk, wv, wo, w1, w2, wqkvt, wot, w1t, w2t, x, g1, be1, xn);
    gemm_mfma<GM_HEAD, 4, 2><<<dim3(12, 64), 256, 0, stream>>>(
        xn, wqkvt, bq, bk, bv, nullptr, nullptr, qb, kb, vb, M_, 768, 256);
    attn_mfma6<<<dim3(N_ / 32, H_, B_), 256, 0, stream>>>(qb, kb, vb, mask, pacc, pl);
    combine_attn<<<(M_ * D_) / (256 * 8), 256, 0, stream>>>(
        pacc, pacc + (size_t)M_ * D_, pl, pl + (size_t)M_ * H_, ao);
    gemm_mfma<GM_RES, 4, 2><<<dim3(4, 64), 256, 0, stream>>>(
        ao, wot, bo, nullptr, nullptr, x, x2, nullptr, nullptr, nullptr, M_, 256, 256);
    ln_kernel<<<M_ / 4, 256, 0, stream>>>(x2, g2, be2, hn);
    gemm_mfma<GM_GELU, 4, 2><<<dim3(16, 64), 256, 0, stream>>>(
        hn, w1t, b1, nullptr, nullptr, nullptr, h1, nullptr, nullptr, nullptr, M_, 1024, 256);
    gemm_mfma<GM_RES, 4, 2><<<dim3(4, 64), 256, 0, stream>>>(
        h1, w2t, b2, nullptr, nullptr, x2, out, nullptr, nullptr, nullptr, M_, 256, 1024);
}

// Round 9
// 129.694 us; speedup vs baseline: 1.4643x; 1.2944x over previous
//
#include <hip/hip_runtime.h>
#include <hip/hip_bf16.h>
#include <math.h>

#define B_ 4
#define N_ 2048
#define D_ 256
#define H_ 8
#define HD_ 32
#define F_ 1024
#define M_ (B_*N_)
#define EPS_ 1e-5f
#define VSTR 72

typedef __attribute__((ext_vector_type(8))) short short8;
typedef __attribute__((ext_vector_type(4))) float f32x4;

// log2(e)/sqrt(32): folded into Q so softmax uses exp2 directly
#define QSC 0.2550565499f

#if __has_builtin(__builtin_amdgcn_exp2f)
__device__ inline float fexp2(float x) { return __builtin_amdgcn_exp2f(x); }
#else
__device__ inline float fexp2(float x) { float r; asm("v_exp_f32 %0, %1" : "=v"(r) : "v"(x)); return r; }
#endif
#if __has_builtin(__builtin_amdgcn_rcpf)
__device__ inline float frcp(float x) { return __builtin_amdgcn_rcpf(x); }
#else
__device__ inline float frcp(float x) { float r; asm("v_rcp_f32 %0, %1" : "=v"(r) : "v"(x)); return r; }
#endif

__device__ inline unsigned short f2bf(float f) {
    union { float f; unsigned u; } x; x.f = f;
    unsigned r = x.u + 0x7fff + ((x.u >> 16) & 1);
    return (unsigned short)(r >> 16);
}

__device__ inline unsigned pk_bf16(float a, float b) {
    union { __hip_bfloat162 h; unsigned u; } c;
    c.h = __float22bfloat162_rn(float2{a, b});
    return c.u;
}

// exact-GELU via Abramowitz-Stegun 7.1.26 erf (|eps| < 1.5e-7), raw v_exp/v_rcp
__device__ inline float gelu_f(float x) {
    float ax = fabsf(x);
    float z = ax * 0.70710678118654752f;
    float t = frcp(fmaf(0.3275911f, z, 1.0f));
    float e = fexp2(-z * z * 1.4426950408889634f);
    float poly = t * fmaf(t, fmaf(t, fmaf(t, fmaf(t, 1.061405429f, -1.453152027f),
                     1.421413741f), -0.284496736f), 0.254829592f);
    float erfv = 1.0f - poly * e;
    float s = (x < 0.f) ? -erfv : erfv;
    return 0.5f * x * (1.0f + s);
}

__device__ inline void async_copy16(const void* g, void* l) {
    __builtin_amdgcn_global_load_lds(
        (const __attribute__((address_space(1))) void*)g,
        (__attribute__((address_space(3))) void*)l, 16, 0, 0);
}

// ---------------- LayerNorm body: one wave per row, 4 rows/block -------------
__device__ inline void ln_rows(const float* __restrict__ x,
        const float* __restrict__ g, const float* __restrict__ be,
        unsigned short* __restrict__ out, int blk) {
    int w = threadIdx.x >> 6, lane = threadIdx.x & 63;
    int row = blk * 4 + w;
    float4 v = *(const float4*)&x[(size_t)row * D_ + lane * 4];
    float s  = v.x + v.y + v.z + v.w;
    float s2 = v.x * v.x + v.y * v.y + v.z * v.z + v.w * v.w;
    #pragma unroll
    for (int off = 1; off < 64; off <<= 1) {
        s  += __shfl_xor(s,  off, 64);
        s2 += __shfl_xor(s2, off, 64);
    }
    float mu  = s * (1.0f / D_);
    float var = s2 * (1.0f / D_) - mu * mu;
    float r = rsqrtf(var + EPS_);
    float4 gv = *(const float4*)&g[lane * 4];
    float4 bv = *(const float4*)&be[lane * 4];
    ushort4 u;
    u.x = f2bf((v.x - mu) * r * gv.x + bv.x);
    u.y = f2bf((v.y - mu) * r * gv.y + bv.y);
    u.z = f2bf((v.z - mu) * r * gv.z + bv.z);
    u.w = f2bf((v.w - mu) * r * gv.w + bv.w);
    *(ushort4*)&out[(size_t)row * D_ + lane * 4] = u;
}

__global__ __launch_bounds__(256) void ln_kernel(const float* __restrict__ x,
        const float* __restrict__ g, const float* __restrict__ be,
        unsigned short* __restrict__ out) {
    ln_rows(x, g, be, out, blockIdx.x);
}

// ---------------- fused prep: pack_adj | weight transpose | LN1 --------------
// blocks [0,4096): pack adj bits (16 ints -> u16 per thread);
// [4096,4864): transposes; [4864,6912): ln1
__global__ __launch_bounds__(256) void prep_kernel(
        const int* __restrict__ adj, unsigned short* __restrict__ mask16,
        const float* __restrict__ wq, const float* __restrict__ wk,
        const float* __restrict__ wv, const float* __restrict__ wo,
        const float* __restrict__ w1, const float* __restrict__ w2,
        unsigned short* __restrict__ wqkvt, unsigned short* __restrict__ wot,
        unsigned short* __restrict__ w1t, unsigned short* __restrict__ w2t,
        const float* __restrict__ x, const float* __restrict__ g1,
        const float* __restrict__ be1, unsigned short* __restrict__ xn) {
    __shared__ float t[32][33];
    int id = blockIdx.x;
    if (id < 4096) {
        int g = id * 256 + threadIdx.x;            // u16 chunk index
        const int4* ap = (const int4*)adj + (size_t)g * 4;
        unsigned bits = 0;
        #pragma unroll
        for (int i = 0; i < 4; i++) {
            int4 v = ap[i];
            bits |= (v.x != 0 ? 1u : 0u) << (4 * i + 0);
            bits |= (v.y != 0 ? 1u : 0u) << (4 * i + 1);
            bits |= (v.z != 0 ? 1u : 0u) << (4 * i + 2);
            bits |= (v.w != 0 ? 1u : 0u) << (4 * i + 3);
        }
        mask16[g] = (unsigned short)bits;
        return;
    }
    if (id >= 4864) {
        ln_rows(x, g1, be1, xn, id - 4864);
        return;
    }
    id -= 4096;
    const float* W; unsigned short* Wt; int K, Nc, n0, k0;
    if (id < 256) {
        int m = id >> 6, l = id & 63;
        K = 256; Nc = 256; n0 = (l & 7) * 32; k0 = (l >> 3) * 32;
        W  = m == 0 ? wq : (m == 1 ? wk : (m == 2 ? wv : wo));
        Wt = m == 0 ? wqkvt : (m == 1 ? wqkvt + 65536 : (m == 2 ? wqkvt + 131072 : wot));
    } else if (id < 512) {
        int l = id - 256; K = 256; Nc = 1024; n0 = (l & 31) * 32; k0 = (l >> 5) * 32;
        W = w1; Wt = w1t;
    } else {
        int l = id - 512; K = 1024; Nc = 256; n0 = (l & 7) * 32; k0 = (l >> 3) * 32;
        W = w2; Wt = w2t;
    }
    int tx = threadIdx.x & 31, ty = threadIdx.x >> 5;   // 32 x 8
    #pragma unroll
    for (int i = 0; i < 4; i++)
        t[ty + i * 8][tx] = W[(size_t)(k0 + ty + i * 8) * Nc + n0 + tx];
    __syncthreads();
    #pragma unroll
    for (int i = 0; i < 4; i++)
        Wt[(size_t)(n0 + ty + i * 8) * K + k0 + tx] = f2bf(t[tx][ty + i * 8]);
}

// ---------------- bf16 MFMA GEMM, double-buffered, 1 barrier / K-step -------
#define GM_HEAD 0   // scatter bf16 to q/k/v (B,H,N,HD); Nc=768 fused; q pre-scaled
#define GM_RES  1   // f32 out, + bias + res
#define GM_GELU 2   // bf16 out, gelu(acc+bias)

template<int MODE, int MI, int NI>
__global__ __launch_bounds__(256) void gemm_mfma(
        const unsigned short* __restrict__ A,
        const unsigned short* __restrict__ Bt,
        const float* __restrict__ bias, const float* __restrict__ bias2,
        const float* __restrict__ bias3, const float* __restrict__ res,
        void* __restrict__ Cout,
        unsigned short* __restrict__ q_out, unsigned short* __restrict__ k_out,
        unsigned short* __restrict__ v_out, int M, int Nc, int K) {
    constexpr int BM = MI * 32, BN = NI * 32;
    __shared__ __align__(16) unsigned short Abuf[2][BM * 32];
    __shared__ __align__(16) unsigned short Bbuf[2][BN * 32];
    int tid = threadIdx.x, w = tid >> 6, lane = tid & 63;
    int lr = lane & 15, lg = lane >> 4;
    int wy = w >> 1, wx = w & 1;
    int m0 = blockIdx.y * BM, n0 = blockIdx.x * BN;
    f32x4 acc[MI][NI] = {};

    int srow = lane >> 2;
    int schunk = lane & 3;

    auto STAGE = [&](int k0, int bi) {
        #pragma unroll
        for (int i = 0; i < BM / 64; i++) {
            int ar = i * 64 + w * 16 + srow;
            int ac = schunk ^ ((ar >> 1) & 3);
            async_copy16(A + (size_t)(m0 + ar) * K + k0 + ac * 8,
                         &Abuf[bi][(i * 64 + w * 16) * 32]);
        }
        #pragma unroll
        for (int i = 0; i < BN / 64; i++) {
            int br = i * 64 + w * 16 + srow;
            int bc = schunk ^ ((br >> 1) & 3);
            async_copy16(Bt + (size_t)(n0 + br) * K + k0 + bc * 8,
                         &Bbuf[bi][(i * 64 + w * 16) * 32]);
        }
    };

    int nkt = K / 32;
    STAGE(0, 0);
    for (int kt = 0; kt < nkt; kt++) {
        __syncthreads();                    // buf[kt&1] staged (barrier drains vmcnt)
        int cur = kt & 1;
        if (kt + 1 < nkt) STAGE((kt + 1) * 32, cur ^ 1);

        short8 af[MI], bf[NI];
        #pragma unroll
        for (int mi = 0; mi < MI; mi++) {
            int r = wy * (MI * 16) + mi * 16 + lr;
            int c = lg ^ ((r >> 1) & 3);
            af[mi] = *(const short8*)&Abuf[cur][r * 32 + c * 8];
        }
        #pragma unroll
        for (int ni = 0; ni < NI; ni++) {
            int r = wx * (NI * 16) + ni * 16 + lr;
            int c = lg ^ ((r >> 1) & 3);
            bf[ni] = *(const short8*)&Bbuf[cur][r * 32 + c * 8];
        }
        #pragma unroll
        for (int mi = 0; mi < MI; mi++)
            #pragma unroll
            for (int ni = 0; ni < NI; ni++)
                acc[mi][ni] = __builtin_amdgcn_mfma_f32_16x16x32_bf16(
                        af[mi], bf[ni], acc[mi][ni], 0, 0, 0);
    }

    #pragma unroll
    for (int mi = 0; mi < MI; mi++) {
        #pragma unroll
        for (int r = 0; r < 4; r++) {
            int grow = m0 + wy * (MI * 16) + mi * 16 + lg * 4 + r;
            #pragma unroll
            for (int ni = 0; ni < NI; ni++) {
                int gcol = n0 + wx * (NI * 16) + ni * 16 + lr;
                float val = acc[mi][ni][r];
                if (MODE == GM_HEAD) {
                    int which = gcol >> 8, nn = gcol & 255;
                    const float* bp = which == 0 ? bias : (which == 1 ? bias2 : bias3);
                    val += bp[nn];
                    if (which == 0) val *= QSC;   // fold log2e/sqrt(HD) into Q
                    unsigned short* dst = which == 0 ? q_out : (which == 1 ? k_out : v_out);
                    int bb = grow >> 11, rr = grow & (N_ - 1);
                    int hh = nn >> 5, dd = nn & 31;
                    dst[((((size_t)bb * H_ + hh) * N_) + rr) * HD_ + dd] = f2bf(val);
                } else if (MODE == GM_RES) {
                    val += bias[gcol] + res[(size_t)grow * Nc + gcol];
                    ((float*)Cout)[(size_t)grow * Nc + gcol] = val;
                } else {
                    val = gelu_f(val + bias[gcol]);
                    ((unsigned short*)Cout)[(size_t)grow * Nc + gcol] = f2bf(val);
                }
            }
        }
    }
}

// ---------------- MFMA flash attention v9 -----------------------------------
// Non-split, 4 waves / 64 q-rows per block, KVBLK=64 dbuf, zero-shuffle P
// (key-permuted V: phys key p=[kc|u|lg|r] -> V slot sigma=[kc|lg|u|r]),
// max-free softmax with raw v_exp_f32, direct bf16 output.
__global__ __launch_bounds__(256) void attn_mfma7(
        const unsigned short* __restrict__ q, const unsigned short* __restrict__ k,
        const unsigned short* __restrict__ v, const unsigned long long* __restrict__ mask,
        unsigned short* __restrict__ ao) {
    __shared__ __align__(16) unsigned short Kb[2][64 * 32];   // K rows, chunk-swizzled
    __shared__ __align__(16) unsigned short Vt[2][32 * VSTR]; // V^T [d][sigma]
    int b = blockIdx.z, h = blockIdx.y;
    int q0 = blockIdx.x * 64;
    int tid = threadIdx.x, w = tid >> 6, lane = tid & 63;
    int lr = lane & 15, lg = lane >> 4;
    size_t bh = (size_t)(b * H_ + h);
    const unsigned short* qbp = q + bh * N_ * HD_;
    const unsigned short* kbp = k + bh * N_ * HD_;
    const unsigned short* vbp = v + bh * N_ * HD_;

    short8 qf = *(const short8*)&qbp[(size_t)(q0 + w * 16 + lr) * HD_ + lg * 8];
    const unsigned long long* mrow = mask + ((size_t)b * N_ + q0 + w * 16 + lr) * (N_ / 64);

    int swz = (lr & 3) ^ ((lr >> 2) & 3);          // K read chunk XOR
    int sr = lane >> 2, sc = lane & 3;             // K staging within wave's 16 rows
    int ssw = (sr & 3) ^ ((sr >> 2) & 3);
    const unsigned short* ksrc = kbp + (size_t)(w * 16 + sr) * HD_ + (sc ^ ssw) * 8;
    int va = tid & 31, vd = tid >> 5;              // V: phys rows {2va,2va+1}, d [vd*4,+4)
    const unsigned short* vsrc = vbp + (size_t)(2 * va) * HD_ + vd * 4;
    int p2 = 2 * va;                               // sigma: [kc|u|lg|r] -> [kc|lg|u|r]
    int sig = (p2 & 35) | ((p2 & 12) << 1) | ((p2 & 16) >> 2);

    f32x4 acc0 = {}, acc1 = {};
    f32x4 zero = {};
    float l0a = 0.f, l1a = 0.f;
    const int NT = N_ / 64;

    // ---- prologue: stage tile 0 into buffer 0 ----
    {
        ushort4 v0p = *(const ushort4*)vsrc;
        ushort4 v1p = *(const ushort4*)(vsrc + HD_);
        async_copy16(ksrc, &Kb[0][w * 16 * 32]);
        *(unsigned*)&Vt[0][(vd * 4 + 0) * VSTR + sig] = ((unsigned)v1p.x << 16) | v0p.x;
        *(unsigned*)&Vt[0][(vd * 4 + 1) * VSTR + sig] = ((unsigned)v1p.y << 16) | v0p.y;
        *(unsigned*)&Vt[0][(vd * 4 + 2) * VSTR + sig] = ((unsigned)v1p.z << 16) | v0p.z;
        *(unsigned*)&Vt[0][(vd * 4 + 3) * VSTR + sig] = ((unsigned)v1p.w << 16) | v0p.w;
    }
    unsigned long long mk_cur = mrow[0], mk_next = 0;
    ushort4 v0n = {}, v1n = {};

    for (int t = 0; t < NT; t++) {
        __syncthreads();                        // tile t staged (drains vmcnt+lgkm)
        int cur = t & 1;
        if (t + 1 < NT) {                       // prefetch t+1 (flies under compute)
            size_t koff = (size_t)(t + 1) * 64 * HD_;
            v0n = *(const ushort4*)(vsrc + koff);
            v1n = *(const ushort4*)(vsrc + koff + HD_);
            async_copy16(ksrc + koff, &Kb[cur ^ 1][w * 16 * 32]);
            mk_next = mrow[t + 1];
        }

        // S^T = K @ Q^T : lane (lr=q, lg) gets s for phys k = j*16 + lg*4 + r
        f32x4 s[4];
        #pragma unroll
        for (int j = 0; j < 4; j++) {
            short8 kf = *(const short8*)&Kb[cur][(j * 16 + lr) * 32 + ((lg ^ swz) * 8)];
            s[j] = __builtin_amdgcn_mfma_f32_16x16x32_bf16(kf, qf, zero, 0, 0, 0);
        }

        // max-free masked softmax numerator: select to -200 then raw v_exp (-> +0)
        unsigned mlo = (unsigned)(mk_cur >> (lg * 4));
        unsigned mhi = (unsigned)(mk_cur >> (lg * 4 + 32));
        #pragma unroll
        for (int j = 0; j < 4; j++) {
            unsigned mw = (j & 2) ? mhi : mlo;
            #pragma unroll
            for (int r = 0; r < 4; r++) {
                float sv = ((mw >> ((j & 1) * 16 + r)) & 1) ? s[j][r] : -200.f;
                float pv = fexp2(sv);
                s[j][r] = pv;
                if (j < 2) l0a += pv; else l1a += pv;
            }
        }

        // P is already the PV A-fragment (key-permuted V): pack in-register
        union { short8 v8; unsigned u[4]; } pf0, pf1;
        pf0.u[0] = pk_bf16(s[0][0], s[0][1]); pf0.u[1] = pk_bf16(s[0][2], s[0][3]);
        pf0.u[2] = pk_bf16(s[1][0], s[1][1]); pf0.u[3] = pk_bf16(s[1][2], s[1][3]);
        pf1.u[0] = pk_bf16(s[2][0], s[2][1]); pf1.u[1] = pk_bf16(s[2][2], s[2][3]);
        pf1.u[2] = pk_bf16(s[3][0], s[3][1]); pf1.u[3] = pk_bf16(s[3][2], s[3][3]);

        short8 vfA0 = *(const short8*)&Vt[cur][lr * VSTR + lg * 8];
        short8 vfB0 = *(const short8*)&Vt[cur][(lr + 16) * VSTR + lg * 8];
        short8 vfA1 = *(const short8*)&Vt[cur][lr * VSTR + 32 + lg * 8];
        short8 vfB1 = *(const short8*)&Vt[cur][(lr + 16) * VSTR + 32 + lg * 8];
        acc0 = __builtin_amdgcn_mfma_f32_16x16x32_bf16(pf0.v8, vfA0, acc0, 0, 0, 0);
        acc1 = __builtin_amdgcn_mfma_f32_16x16x32_bf16(pf0.v8, vfB0, acc1, 0, 0, 0);
        acc0 = __builtin_amdgcn_mfma_f32_16x16x32_bf16(pf1.v8, vfA1, acc0, 0, 0, 0);
        acc1 = __builtin_amdgcn_mfma_f32_16x16x32_bf16(pf1.v8, vfB1, acc1, 0, 0, 0);

        if (t + 1 < NT) {                       // late V write (loads landed under compute)
            *(unsigned*)&Vt[cur ^ 1][(vd * 4 + 0) * VSTR + sig] = ((unsigned)v1n.x << 16) | v0n.x;
            *(unsigned*)&Vt[cur ^ 1][(vd * 4 + 1) * VSTR + sig] = ((unsigned)v1n.y << 16) | v0n.y;
            *(unsigned*)&Vt[cur ^ 1][(vd * 4 + 2) * VSTR + sig] = ((unsigned)v1n.z << 16) | v0n.z;
            *(unsigned*)&Vt[cur ^ 1][(vd * 4 + 3) * VSTR + sig] = ((unsigned)v1n.w << 16) | v0n.w;
        }
        mk_cur = mk_next;
    }

    // per-q-row l (lane-space q = lr), normalize, write bf16
    float l = l0a + l1a;
    l += __shfl_xor(l, 16, 64);
    l += __shfl_xor(l, 32, 64);
    float linv = (l > 0.f) ? 1.0f / l : 0.f;
    #pragma unroll
    for (int r = 0; r < 4; r++) {
        float ir = __shfl(linv, lg * 4 + r, 64);
        int row = q0 + w * 16 + lg * 4 + r;
        unsigned short* op = ao + ((size_t)(b * N_) + row) * D_ + h * HD_;
        op[lr]      = f2bf(acc0[r] * ir);
        op[lr + 16] = f2bf(acc1[r] * ir);
    }
}

// ---------------- Launch -----------------------------------------------------
extern "C" void kernel_launch(void* const* d_in, const int* in_sizes, int n_in,
                              void* d_out, int out_size, void* d_ws, size_t ws_size,
                              hipStream_t stream) {
    const float* x   = (const float*)d_in[0];
    const int*   adj = (const int*)d_in[1];
    const float* wq  = (const float*)d_in[2];
    const float* bq  = (const float*)d_in[3];
    const float* wk  = (const float*)d_in[4];
    const float* bk  = (const float*)d_in[5];
    const float* wv  = (const float*)d_in[6];
    const float* bv  = (const float*)d_in[7];
    const float* wo  = (const float*)d_in[8];
    const float* bo  = (const float*)d_in[9];
    const float* g1  = (const float*)d_in[10];
    const float* be1 = (const float*)d_in[11];
    const float* g2  = (const float*)d_in[12];
    const float* be2 = (const float*)d_in[13];
    const float* w1  = (const float*)d_in[14];
    const float* b1  = (const float*)d_in[15];
    const float* w2  = (const float*)d_in[16];
    const float* b2  = (const float*)d_in[17];
    float* out = (float*)d_out;
    char* base = (char*)d_ws;

    const size_t MB = (size_t)1 << 20;
    unsigned long long* mask = (unsigned long long*)(base);     // 2 MB
    unsigned short* xn     = (unsigned short*)(base + 2*MB);    // 4 MB
    unsigned short* qb     = (unsigned short*)(base + 6*MB);    // 4 MB
    unsigned short* kb     = (unsigned short*)(base + 10*MB);   // 4 MB
    unsigned short* vb     = (unsigned short*)(base + 14*MB);   // 4 MB
    unsigned short* ao     = (unsigned short*)(base + 18*MB);   // 4 MB
    float*          x2     = (float*)(base + 22*MB);            // 8 MB
    unsigned short* hn     = (unsigned short*)(base + 30*MB);   // 4 MB
    unsigned short* h1     = (unsigned short*)(base + 34*MB);   // 16 MB (FFN)
    unsigned short* wqkvt  = (unsigned short*)(base + 51*MB);   // 384 KB
    unsigned short* wot    = (unsigned short*)(base + 51*MB + 394240);   // 128 KB
    unsigned short* w1t    = (unsigned short*)(base + 52*MB);   // 512 KB
    unsigned short* w2t    = (unsigned short*)(base + 52*MB + 524288);   // 512 KB

    prep_kernel<<<4096 + 768 + 2048, 256, 0, stream>>>(
        adj, (unsigned short*)mask, wq, wk, wv, wo, w1, w2,
        wqkvt, wot, w1t, w2t, x, g1, be1, xn);
    gemm_mfma<GM_HEAD, 4, 2><<<dim3(12, 64), 256, 0, stream>>>(
        xn, wqkvt, bq, bk, bv, nullptr, nullptr, qb, kb, vb, M_, 768, 256);
    attn_mfma7<<<dim3(N_ / 64, H_, B_), 256, 0, stream>>>(qb, kb, vb, mask, ao);
    gemm_mfma<GM_RES, 4, 2><<<dim3(4, 64), 256, 0, stream>>>(
        ao, wot, bo, nullptr, nullptr, x, x2, nullptr, nullptr, nullptr, M_, 256, 256);
    ln_kernel<<<M_ / 4, 256, 0, stream>>>(x2, g2, be2, hn);
    gemm_mfma<GM_GELU, 4, 2><<<dim3(16, 64), 256, 0, stream>>>(
        hn, w1t, b1, nullptr, nullptr, nullptr, h1, nullptr, nullptr, nullptr, M_, 1024, 256);
    gemm_mfma<GM_RES, 4, 2><<<dim3(4, 64), 256, 0, stream>>>(
        h1, w2t, b2, nullptr, nullptr, x2, out, nullptr, nullptr, nullptr, M_, 256, 1024);
}